// Round 1
// baseline (1164.567 us; speedup 1.0000x reference)
//
#include <hip/hip_runtime.h>

// ---------------------------------------------------------------------------
// GCN: out = A(A(A(xW1)+b1)relu W2 +b2)relu W3 + b3, A = D^-1/2 (Adj+I) D^-1/2
// Device-side CSR build (count -> scan -> fill), fp32 tiled GEMMs, pull-style
// aggregation (no float atomics).
// ---------------------------------------------------------------------------

__global__ void count_kernel(const int* __restrict__ ei, int E, int* __restrict__ cnt) {
    int e = blockIdx.x * 256 + threadIdx.x;
    if (e < E) atomicAdd(&cnt[ei[E + e]], 1);
}

__global__ void dinv_kernel(const int* __restrict__ cnt, float* __restrict__ dinv, int n) {
    int i = blockIdx.x * 256 + threadIdx.x;
    if (i < n) dinv[i] = rsqrtf((float)(cnt[i] + 1));  // +1 self loop; always > 0
}

// exclusive scan of cnt[0..n) into row_start[0..n), block handles 1024 elems
__global__ __launch_bounds__(256) void scan1_kernel(const int* __restrict__ cnt,
                                                    int* __restrict__ row_start,
                                                    int* __restrict__ bsum, int n) {
    __shared__ int sh[256];
    int t = threadIdx.x;
    int base = blockIdx.x * 1024 + t * 4;
    int v0 = 0, v1 = 0, v2 = 0, v3 = 0;
    if (base + 0 < n) v0 = cnt[base + 0];
    if (base + 1 < n) v1 = cnt[base + 1];
    if (base + 2 < n) v2 = cnt[base + 2];
    if (base + 3 < n) v3 = cnt[base + 3];
    int s = v0 + v1 + v2 + v3;
    sh[t] = s;
    __syncthreads();
    for (int off = 1; off < 256; off <<= 1) {
        int add = (t >= off) ? sh[t - off] : 0;
        __syncthreads();
        sh[t] += add;
        __syncthreads();
    }
    int excl = sh[t] - s;
    if (t == 255) bsum[blockIdx.x] = sh[255];
    int p = excl;
    if (base + 0 < n) row_start[base + 0] = p; p += v0;
    if (base + 1 < n) row_start[base + 1] = p; p += v1;
    if (base + 2 < n) row_start[base + 2] = p; p += v2;
    if (base + 3 < n) row_start[base + 3] = p;
}

__global__ void scan2_kernel(const int* __restrict__ bsum, int* __restrict__ boff,
                             int* __restrict__ row_start, int nb, int n) {
    if (threadIdx.x == 0 && blockIdx.x == 0) {
        int run = 0;
        for (int b = 0; b < nb; b++) { boff[b] = run; run += bsum[b]; }
        row_start[n] = run;   // == E
    }
}

__global__ __launch_bounds__(256) void scan3_kernel(int* __restrict__ row_start,
                                                    int* __restrict__ cursor,
                                                    const int* __restrict__ boff, int n) {
    int t = threadIdx.x;
    int base = blockIdx.x * 1024 + t * 4;
    int off = boff[blockIdx.x];
#pragma unroll
    for (int i = 0; i < 4; i++) {
        int idx = base + i;
        if (idx < n) {
            int v = row_start[idx] + off;
            row_start[idx] = v;
            cursor[idx] = v;
        }
    }
}

__global__ void fill_kernel(const int* __restrict__ ei, int E, int* __restrict__ cursor,
                            const float* __restrict__ dinv, int* __restrict__ csr_src,
                            float* __restrict__ csr_coef) {
    int e = blockIdx.x * 256 + threadIdx.x;
    if (e < E) {
        int s = ei[e], d = ei[E + e];
        int pos = atomicAdd(&cursor[d], 1);
        csr_src[pos] = s;
        csr_coef[pos] = dinv[s] * dinv[d];
    }
}

// ---------------------------------------------------------------------------
// fp32 GEMM: out[n x 128] = A[n x 128] @ W[128 x 128].
// 64x64 output tile / block (256 thr), 4x4 register tile / thread.
// LDS holds x-tile transposed [k][row] and W-tile [k][col], XOR-swizzled.
// ---------------------------------------------------------------------------
__global__ __launch_bounds__(256) void gemm128_kernel(const float* __restrict__ A,
                                                      const float* __restrict__ W,
                                                      float* __restrict__ out, int n) {
    __shared__ float xs[128][64];  // [k][r], r swizzled by ((k>>2)&7)<<2
    __shared__ float ws[128][64];  // [k][c], c swizzled by ((k&7))<<2
    const int t = threadIdx.x;
    const int rowBase = blockIdx.x * 64;
    const int colBase = blockIdx.y * 64;

    // stage x tile (transposed store)
#pragma unroll
    for (int j = 0; j < 8; j++) {
        int i = t + j * 256;        // 0..2047 float4 tiles: r = i>>5, kq = i&31
        int r = i >> 5, kq = i & 31;
        int grow = rowBase + r;
        float4 v = make_float4(0.f, 0.f, 0.f, 0.f);
        if (grow < n) v = *(const float4*)(A + (size_t)grow * 128 + kq * 4);
        const float* pv = (const float*)&v;
#pragma unroll
        for (int m = 0; m < 4; m++) {
            int k = kq * 4 + m;
            xs[k][r ^ (((k >> 2) & 7) << 2)] = pv[m];
        }
    }
    // stage W tile
#pragma unroll
    for (int j = 0; j < 8; j++) {
        int i = t + j * 256;        // k = i>>4, cq = i&15
        int k = i >> 4, cq = i & 15;
        float4 v = *(const float4*)(W + (size_t)k * 128 + colBase + cq * 4);
        *(float4*)&ws[k][(cq * 4) ^ ((k & 7) << 2)] = v;
    }
    __syncthreads();

    const int tx = t & 15, ty = t >> 4;
    const int ra = ty * 4, ca = tx * 4;
    float acc[4][4];
#pragma unroll
    for (int i = 0; i < 4; i++)
#pragma unroll
        for (int j = 0; j < 4; j++) acc[i][j] = 0.f;

#pragma unroll 8
    for (int k = 0; k < 128; k++) {
        int sxz = ((k >> 2) & 7) << 2;
        int swz = (k & 7) << 2;
        float4 a = *(const float4*)&xs[k][ra ^ sxz];
        float4 b = *(const float4*)&ws[k][ca ^ swz];
        const float* pa = (const float*)&a;
        const float* pb = (const float*)&b;
#pragma unroll
        for (int i = 0; i < 4; i++)
#pragma unroll
            for (int j = 0; j < 4; j++) acc[i][j] += pa[i] * pb[j];
    }

#pragma unroll
    for (int i = 0; i < 4; i++) {
        int grow = rowBase + ra + i;
        if (grow < n) {
            float4 v = make_float4(acc[i][0], acc[i][1], acc[i][2], acc[i][3]);
            *(float4*)(out + (size_t)grow * 128 + colBase + ca) = v;
        }
    }
}

// out[n x 40] = A[n x 128] @ W[128 x 40]; one wave per row (lanes 0..39 active)
__global__ __launch_bounds__(256) void gemm40_kernel(const float* __restrict__ A,
                                                     const float* __restrict__ W,
                                                     float* __restrict__ out, int n) {
    int t = threadIdx.x;
    int row = blockIdx.x * 4 + (t >> 6);
    int lane = t & 63;
    if (row >= n) return;
    const float* xr = A + (size_t)row * 128;
    float acc = 0.f;
#pragma unroll 8
    for (int k = 0; k < 128; k++) {
        float xv = xr[k];
        float wv = (lane < 40) ? W[k * 40 + lane] : 0.f;
        acc = fmaf(xv, wv, acc);
    }
    if (lane < 40) out[(size_t)row * 40 + lane] = acc;
}

// pull aggregation, 128 features: out[i] = dinv[i]^2*hw[i] + sum_e coef*hw[src] + b
__global__ __launch_bounds__(128) void agg128_kernel(const float* __restrict__ hw,
                                                     const float* __restrict__ dinv,
                                                     const int* __restrict__ row_start,
                                                     const int* __restrict__ csr_src,
                                                     const float* __restrict__ csr_coef,
                                                     const float* __restrict__ bias,
                                                     float* __restrict__ out, int n,
                                                     int do_relu) {
    int i = blockIdx.x;
    int f = threadIdx.x;
    float di = dinv[i];
    float acc = di * di * hw[(size_t)i * 128 + f];
    int e0 = row_start[i], e1 = row_start[i + 1];
    for (int e = e0; e < e1; e++) {
        int s = csr_src[e];
        float c = csr_coef[e];
        acc = fmaf(c, hw[(size_t)s * 128 + f], acc);
    }
    float r = acc + bias[f];
    if (do_relu) r = fmaxf(r, 0.f);
    out[(size_t)i * 128 + f] = r;
}

// pull aggregation, 40 features, writes final logits
__global__ __launch_bounds__(64) void agg40_kernel(const float* __restrict__ hw,
                                                   const float* __restrict__ dinv,
                                                   const int* __restrict__ row_start,
                                                   const int* __restrict__ csr_src,
                                                   const float* __restrict__ csr_coef,
                                                   const float* __restrict__ bias,
                                                   float* __restrict__ out, int n) {
    int i = blockIdx.x;
    int f = threadIdx.x;
    if (f >= 40) return;
    float di = dinv[i];
    float acc = di * di * hw[(size_t)i * 40 + f];
    int e0 = row_start[i], e1 = row_start[i + 1];
    for (int e = e0; e < e1; e++) {
        int s = csr_src[e];
        float c = csr_coef[e];
        acc = fmaf(c, hw[(size_t)s * 40 + f], acc);
    }
    out[(size_t)i * 40 + f] = acc + bias[f];
}

extern "C" void kernel_launch(void* const* d_in, const int* in_sizes, int n_in,
                              void* d_out, int out_size, void* d_ws, size_t ws_size,
                              hipStream_t stream) {
    const float* x  = (const float*)d_in[0];
    const int*   ei = (const int*)d_in[1];
    const float* W1 = (const float*)d_in[2];
    const float* b1 = (const float*)d_in[3];
    const float* W2 = (const float*)d_in[4];
    const float* b2 = (const float*)d_in[5];
    const float* W3 = (const float*)d_in[6];
    const float* b3 = (const float*)d_in[7];
    float* out = (float*)d_out;

    const int n = in_sizes[0] / 128;   // 170000
    const int E = in_sizes[1] / 2;     // 1200000

    // workspace carve (256B aligned)
    char* p = (char*)d_ws;
    auto alloc = [&](size_t bytes) { void* r = (void*)p; p += (bytes + 255) & ~(size_t)255; return r; };
    int*   cnt       = (int*)alloc((size_t)n * 4);
    int*   row_start = (int*)alloc((size_t)(n + 1) * 4);
    int*   cursor    = (int*)alloc((size_t)n * 4);
    int*   bsum      = (int*)alloc(1024 * 4);
    int*   boff      = (int*)alloc(1024 * 4);
    float* dinv      = (float*)alloc((size_t)n * 4);
    int*   csr_src   = (int*)alloc((size_t)E * 4);
    float* csr_coef  = (float*)alloc((size_t)E * 4);
    float* bufA      = (float*)alloc((size_t)n * 128 * 4);
    float* bufB      = (float*)alloc((size_t)n * 128 * 4);

    // --- CSR build ---
    hipMemsetAsync(cnt, 0, (size_t)n * 4, stream);
    count_kernel<<<(E + 255) / 256, 256, 0, stream>>>(ei, E, cnt);
    dinv_kernel<<<(n + 255) / 256, 256, 0, stream>>>(cnt, dinv, n);
    int nb = (n + 1023) / 1024;
    scan1_kernel<<<nb, 256, 0, stream>>>(cnt, row_start, bsum, n);
    scan2_kernel<<<1, 64, 0, stream>>>(bsum, boff, row_start, nb, n);
    scan3_kernel<<<nb, 256, 0, stream>>>(row_start, cursor, boff, n);
    fill_kernel<<<(E + 255) / 256, 256, 0, stream>>>(ei, E, cursor, dinv, csr_src, csr_coef);

    dim3 gemm_grid((n + 63) / 64, 2);

    // --- layer 1 ---
    gemm128_kernel<<<gemm_grid, 256, 0, stream>>>(x, W1, bufA, n);
    agg128_kernel<<<n, 128, 0, stream>>>(bufA, dinv, row_start, csr_src, csr_coef, b1, bufB, n, 1);
    // --- layer 2 ---
    gemm128_kernel<<<gemm_grid, 256, 0, stream>>>(bufB, W2, bufA, n);
    agg128_kernel<<<n, 128, 0, stream>>>(bufA, dinv, row_start, csr_src, csr_coef, b2, bufB, n, 1);
    // --- layer 3 (W first: A(hW3) == (Ah)W3, aggregate only 40 features) ---
    gemm40_kernel<<<(n + 3) / 4, 256, 0, stream>>>(bufB, W3, bufA, n);
    agg40_kernel<<<n, 64, 0, stream>>>(bufA, dinv, row_start, csr_src, csr_coef, b3, out, n);
}

// Round 2
// 870.914 us; speedup vs baseline: 1.3372x; 1.3372x over previous
//
#include <hip/hip_runtime.h>

// ---------------------------------------------------------------------------
// GCN: out = A(A(A(xW1)+b1)relu W2 +b2)relu W3 + b3, A = D^-1/2 (Adj+I) D^-1/2
// Device-side CSR build (count -> scan -> fill), fp32 tiled GEMMs, pull-style
// aggregation (no float atomics).
// ---------------------------------------------------------------------------

__global__ void count_kernel(const int* __restrict__ ei, int E, int* __restrict__ cnt) {
    int e = blockIdx.x * 256 + threadIdx.x;
    if (e < E) atomicAdd(&cnt[ei[E + e]], 1);
}

__global__ void dinv_kernel(const int* __restrict__ cnt, float* __restrict__ dinv, int n) {
    int i = blockIdx.x * 256 + threadIdx.x;
    if (i < n) dinv[i] = rsqrtf((float)(cnt[i] + 1));  // +1 self loop; always > 0
}

// exclusive scan of cnt[0..n) into row_start[0..n), block handles 1024 elems
__global__ __launch_bounds__(256) void scan1_kernel(const int* __restrict__ cnt,
                                                    int* __restrict__ row_start,
                                                    int* __restrict__ bsum, int n) {
    __shared__ int sh[256];
    int t = threadIdx.x;
    int base = blockIdx.x * 1024 + t * 4;
    int v0 = 0, v1 = 0, v2 = 0, v3 = 0;
    if (base + 0 < n) v0 = cnt[base + 0];
    if (base + 1 < n) v1 = cnt[base + 1];
    if (base + 2 < n) v2 = cnt[base + 2];
    if (base + 3 < n) v3 = cnt[base + 3];
    int s = v0 + v1 + v2 + v3;
    sh[t] = s;
    __syncthreads();
    for (int off = 1; off < 256; off <<= 1) {
        int add = (t >= off) ? sh[t - off] : 0;
        __syncthreads();
        sh[t] += add;
        __syncthreads();
    }
    int excl = sh[t] - s;
    if (t == 255) bsum[blockIdx.x] = sh[255];
    int p = excl;
    if (base + 0 < n) row_start[base + 0] = p; p += v0;
    if (base + 1 < n) row_start[base + 1] = p; p += v1;
    if (base + 2 < n) row_start[base + 2] = p; p += v2;
    if (base + 3 < n) row_start[base + 3] = p;
}

__global__ void scan2_kernel(const int* __restrict__ bsum, int* __restrict__ boff,
                             int* __restrict__ row_start, int nb, int n) {
    if (threadIdx.x == 0 && blockIdx.x == 0) {
        int run = 0;
        for (int b = 0; b < nb; b++) { boff[b] = run; run += bsum[b]; }
        row_start[n] = run;   // == E
    }
}

__global__ __launch_bounds__(256) void scan3_kernel(int* __restrict__ row_start,
                                                    int* __restrict__ cursor,
                                                    const int* __restrict__ boff, int n) {
    int t = threadIdx.x;
    int base = blockIdx.x * 1024 + t * 4;
    int off = boff[blockIdx.x];
#pragma unroll
    for (int i = 0; i < 4; i++) {
        int idx = base + i;
        if (idx < n) {
            int v = row_start[idx] + off;
            row_start[idx] = v;
            cursor[idx] = v;
        }
    }
}

__global__ void fill_kernel(const int* __restrict__ ei, int E, int* __restrict__ cursor,
                            const float* __restrict__ dinv, int* __restrict__ csr_src,
                            float* __restrict__ csr_coef) {
    int e = blockIdx.x * 256 + threadIdx.x;
    if (e < E) {
        int s = ei[e], d = ei[E + e];
        int pos = atomicAdd(&cursor[d], 1);
        csr_src[pos] = s;
        csr_coef[pos] = dinv[s] * dinv[d];
    }
}

// ---------------------------------------------------------------------------
// fp32 GEMM: out[n x 128] = A[n x 128] @ W[128 x 128].
// 64x64 output tile / block (256 thr), 4x4 register tile / thread.
// LDS holds x-tile transposed [k][row] and W-tile [k][col], XOR-swizzled.
// ---------------------------------------------------------------------------
__global__ __launch_bounds__(256) void gemm128_kernel(const float* __restrict__ A,
                                                      const float* __restrict__ W,
                                                      float* __restrict__ out, int n) {
    __shared__ float xs[128][64];  // [k][r], r swizzled by ((k>>2)&7)<<2
    __shared__ float ws[128][64];  // [k][c], c swizzled by ((k&7))<<2
    const int t = threadIdx.x;
    const int rowBase = blockIdx.x * 64;
    const int colBase = blockIdx.y * 64;

    // stage x tile (transposed store)
#pragma unroll
    for (int j = 0; j < 8; j++) {
        int i = t + j * 256;        // 0..2047 float4 tiles: r = i>>5, kq = i&31
        int r = i >> 5, kq = i & 31;
        int grow = rowBase + r;
        float4 v = make_float4(0.f, 0.f, 0.f, 0.f);
        if (grow < n) v = *(const float4*)(A + (size_t)grow * 128 + kq * 4);
        const float* pv = (const float*)&v;
#pragma unroll
        for (int m = 0; m < 4; m++) {
            int k = kq * 4 + m;
            xs[k][r ^ (((k >> 2) & 7) << 2)] = pv[m];
        }
    }
    // stage W tile
#pragma unroll
    for (int j = 0; j < 8; j++) {
        int i = t + j * 256;        // k = i>>4, cq = i&15
        int k = i >> 4, cq = i & 15;
        float4 v = *(const float4*)(W + (size_t)k * 128 + colBase + cq * 4);
        *(float4*)&ws[k][(cq * 4) ^ ((k & 7) << 2)] = v;
    }
    __syncthreads();

    const int tx = t & 15, ty = t >> 4;
    const int ra = ty * 4, ca = tx * 4;
    float acc[4][4];
#pragma unroll
    for (int i = 0; i < 4; i++)
#pragma unroll
        for (int j = 0; j < 4; j++) acc[i][j] = 0.f;

#pragma unroll 8
    for (int k = 0; k < 128; k++) {
        int sxz = ((k >> 2) & 7) << 2;
        int swz = (k & 7) << 2;
        float4 a = *(const float4*)&xs[k][ra ^ sxz];
        float4 b = *(const float4*)&ws[k][ca ^ swz];
        const float* pa = (const float*)&a;
        const float* pb = (const float*)&b;
#pragma unroll
        for (int i = 0; i < 4; i++)
#pragma unroll
            for (int j = 0; j < 4; j++) acc[i][j] += pa[i] * pb[j];
    }

#pragma unroll
    for (int i = 0; i < 4; i++) {
        int grow = rowBase + ra + i;
        if (grow < n) {
            float4 v = make_float4(acc[i][0], acc[i][1], acc[i][2], acc[i][3]);
            *(float4*)(out + (size_t)grow * 128 + colBase + ca) = v;
        }
    }
}

// ---------------------------------------------------------------------------
// out[n x 40] = A[n x 128] @ W[128 x 40]
// 128 rows x 40 cols per 256-thread block; W transposed in LDS wt[40][132]
// (pad 132 -> float4 reads conflict-free across tx); 4x5 register tile/thread.
// ---------------------------------------------------------------------------
__global__ __launch_bounds__(256) void gemm40_kernel(const float* __restrict__ A,
                                                     const float* __restrict__ W,
                                                     float* __restrict__ out, int n) {
    __shared__ float wt[40][132];
    const int t = threadIdx.x;
    // stage W transposed: W is [128][40] row-major
    for (int i = t; i < 5120; i += 256) {
        int k = i / 40, c = i % 40;
        wt[c][k] = W[i];
    }
    __syncthreads();

    const int tx = t & 7;          // col group: cols 5*tx .. 5*tx+4
    const int ty = t >> 3;         // row group: rows 4*ty .. 4*ty+3
    const int r0 = blockIdx.x * 128 + ty * 4;
    const int c0 = tx * 5;

    bool rv[4];
#pragma unroll
    for (int i = 0; i < 4; i++) rv[i] = (r0 + i) < n;

    float acc[4][5];
#pragma unroll
    for (int i = 0; i < 4; i++)
#pragma unroll
        for (int j = 0; j < 5; j++) acc[i][j] = 0.f;

#pragma unroll 4
    for (int kq = 0; kq < 32; kq++) {
        float4 a[4];
#pragma unroll
        for (int i = 0; i < 4; i++)
            a[i] = rv[i] ? *(const float4*)(A + (size_t)(r0 + i) * 128 + kq * 4)
                         : make_float4(0.f, 0.f, 0.f, 0.f);
        float4 w[5];
#pragma unroll
        for (int j = 0; j < 5; j++)
            w[j] = *(const float4*)&wt[c0 + j][kq * 4];
#pragma unroll
        for (int i = 0; i < 4; i++) {
            const float* pa = (const float*)&a[i];
#pragma unroll
            for (int j = 0; j < 5; j++) {
                const float* pw = (const float*)&w[j];
                acc[i][j] = fmaf(pa[0], pw[0], acc[i][j]);
                acc[i][j] = fmaf(pa[1], pw[1], acc[i][j]);
                acc[i][j] = fmaf(pa[2], pw[2], acc[i][j]);
                acc[i][j] = fmaf(pa[3], pw[3], acc[i][j]);
            }
        }
    }

#pragma unroll
    for (int i = 0; i < 4; i++) {
        if (rv[i]) {
#pragma unroll
            for (int j = 0; j < 5; j++)
                out[(size_t)(r0 + i) * 40 + c0 + j] = acc[i][j];
        }
    }
}

// pull aggregation, 128 features, float4-vectorized: 8 nodes / 256-thr block,
// 32 lanes per node each owning 4 consecutive features.
__global__ __launch_bounds__(256) void agg128_kernel(const float* __restrict__ hw,
                                                     const float* __restrict__ dinv,
                                                     const int* __restrict__ row_start,
                                                     const int* __restrict__ csr_src,
                                                     const float* __restrict__ csr_coef,
                                                     const float* __restrict__ bias,
                                                     float* __restrict__ out, int n,
                                                     int do_relu) {
    int t = threadIdx.x;
    int node = blockIdx.x * 8 + (t >> 5);
    int f = t & 31;
    if (node >= n) return;
    const float4* hw4 = (const float4*)hw;
    float di = dinv[node];
    float s2 = di * di;
    float4 v = hw4[(size_t)node * 32 + f];
    float4 acc = make_float4(v.x * s2, v.y * s2, v.z * s2, v.w * s2);
    int e0 = row_start[node], e1 = row_start[node + 1];
    for (int e = e0; e < e1; e++) {
        int s = csr_src[e];
        float c = csr_coef[e];
        float4 u = hw4[(size_t)s * 32 + f];
        acc.x = fmaf(c, u.x, acc.x);
        acc.y = fmaf(c, u.y, acc.y);
        acc.z = fmaf(c, u.z, acc.z);
        acc.w = fmaf(c, u.w, acc.w);
    }
    float4 b4 = ((const float4*)bias)[f];
    acc.x += b4.x; acc.y += b4.y; acc.z += b4.z; acc.w += b4.w;
    if (do_relu) {
        acc.x = fmaxf(acc.x, 0.f); acc.y = fmaxf(acc.y, 0.f);
        acc.z = fmaxf(acc.z, 0.f); acc.w = fmaxf(acc.w, 0.f);
    }
    ((float4*)out)[(size_t)node * 32 + f] = acc;
}

// pull aggregation, 40 features: 8 nodes / 320-thr block, 1 lane per feature
__global__ __launch_bounds__(320) void agg40_kernel(const float* __restrict__ hw,
                                                    const float* __restrict__ dinv,
                                                    const int* __restrict__ row_start,
                                                    const int* __restrict__ csr_src,
                                                    const float* __restrict__ csr_coef,
                                                    const float* __restrict__ bias,
                                                    float* __restrict__ out, int n) {
    int t = threadIdx.x;
    int node = blockIdx.x * 8 + t / 40;
    int f = t % 40;
    if (node >= n) return;
    float di = dinv[node];
    float acc = di * di * hw[(size_t)node * 40 + f];
    int e0 = row_start[node], e1 = row_start[node + 1];
    for (int e = e0; e < e1; e++) {
        int s = csr_src[e];
        float c = csr_coef[e];
        acc = fmaf(c, hw[(size_t)s * 40 + f], acc);
    }
    out[(size_t)node * 40 + f] = acc + bias[f];
}

extern "C" void kernel_launch(void* const* d_in, const int* in_sizes, int n_in,
                              void* d_out, int out_size, void* d_ws, size_t ws_size,
                              hipStream_t stream) {
    const float* x  = (const float*)d_in[0];
    const int*   ei = (const int*)d_in[1];
    const float* W1 = (const float*)d_in[2];
    const float* b1 = (const float*)d_in[3];
    const float* W2 = (const float*)d_in[4];
    const float* b2 = (const float*)d_in[5];
    const float* W3 = (const float*)d_in[6];
    const float* b3 = (const float*)d_in[7];
    float* out = (float*)d_out;

    const int n = in_sizes[0] / 128;   // 170000
    const int E = in_sizes[1] / 2;     // 1200000

    // workspace carve (256B aligned)
    char* p = (char*)d_ws;
    auto alloc = [&](size_t bytes) { void* r = (void*)p; p += (bytes + 255) & ~(size_t)255; return r; };
    int*   cnt       = (int*)alloc((size_t)n * 4);
    int*   row_start = (int*)alloc((size_t)(n + 1) * 4);
    int*   cursor    = (int*)alloc((size_t)n * 4);
    int*   bsum      = (int*)alloc(1024 * 4);
    int*   boff      = (int*)alloc(1024 * 4);
    float* dinv      = (float*)alloc((size_t)n * 4);
    int*   csr_src   = (int*)alloc((size_t)E * 4);
    float* csr_coef  = (float*)alloc((size_t)E * 4);
    float* bufA      = (float*)alloc((size_t)n * 128 * 4);
    float* bufB      = (float*)alloc((size_t)n * 128 * 4);

    // --- CSR build ---
    hipMemsetAsync(cnt, 0, (size_t)n * 4, stream);
    count_kernel<<<(E + 255) / 256, 256, 0, stream>>>(ei, E, cnt);
    dinv_kernel<<<(n + 255) / 256, 256, 0, stream>>>(cnt, dinv, n);
    int nb = (n + 1023) / 1024;
    scan1_kernel<<<nb, 256, 0, stream>>>(cnt, row_start, bsum, n);
    scan2_kernel<<<1, 64, 0, stream>>>(bsum, boff, row_start, nb, n);
    scan3_kernel<<<nb, 256, 0, stream>>>(row_start, cursor, boff, n);
    fill_kernel<<<(E + 255) / 256, 256, 0, stream>>>(ei, E, cursor, dinv, csr_src, csr_coef);

    dim3 gemm_grid((n + 63) / 64, 2);

    // --- layer 1 ---
    gemm128_kernel<<<gemm_grid, 256, 0, stream>>>(x, W1, bufA, n);
    agg128_kernel<<<(n + 7) / 8, 256, 0, stream>>>(bufA, dinv, row_start, csr_src, csr_coef, b1, bufB, n, 1);
    // --- layer 2 ---
    gemm128_kernel<<<gemm_grid, 256, 0, stream>>>(bufB, W2, bufA, n);
    agg128_kernel<<<(n + 7) / 8, 256, 0, stream>>>(bufA, dinv, row_start, csr_src, csr_coef, b2, bufB, n, 1);
    // --- layer 3 (W first: A(hW3) == (Ah)W3, aggregate only 40 features) ---
    gemm40_kernel<<<(n + 127) / 128, 256, 0, stream>>>(bufB, W3, bufA, n);
    agg40_kernel<<<(n + 7) / 8, 320, 0, stream>>>(bufA, dinv, row_start, csr_src, csr_coef, b3, out, n);
}

// Round 3
// 753.749 us; speedup vs baseline: 1.5450x; 1.1554x over previous
//
#include <hip/hip_runtime.h>

typedef unsigned short u16;
typedef u16   u16x8  __attribute__((ext_vector_type(8)));
typedef u16   u16x4  __attribute__((ext_vector_type(4)));
typedef short short8v __attribute__((ext_vector_type(8)));
typedef float f32x16  __attribute__((ext_vector_type(16)));

__device__ __forceinline__ u16 f2bf(float f) {
    unsigned u = __float_as_uint(f);
    unsigned r = (u + 0x7fffu + ((u >> 16) & 1u)) >> 16;   // round-to-nearest-even
    return (u16)r;
}

// ---------------------------------------------------------------------------
// CSR build: count -> scan -> fill
// ---------------------------------------------------------------------------
__global__ void count_kernel(const int* __restrict__ ei, int E, int* __restrict__ cnt) {
    int e = blockIdx.x * 256 + threadIdx.x;
    if (e < E) atomicAdd(&cnt[ei[E + e]], 1);
}

__global__ void dinv_kernel(const int* __restrict__ cnt, float* __restrict__ dinv, int n) {
    int i = blockIdx.x * 256 + threadIdx.x;
    if (i < n) dinv[i] = rsqrtf((float)(cnt[i] + 1));  // +1 self loop; always > 0
}

__global__ __launch_bounds__(256) void scan1_kernel(const int* __restrict__ cnt,
                                                    int* __restrict__ row_start,
                                                    int* __restrict__ bsum, int n) {
    __shared__ int sh[256];
    int t = threadIdx.x;
    int base = blockIdx.x * 1024 + t * 4;
    int v0 = 0, v1 = 0, v2 = 0, v3 = 0;
    if (base + 0 < n) v0 = cnt[base + 0];
    if (base + 1 < n) v1 = cnt[base + 1];
    if (base + 2 < n) v2 = cnt[base + 2];
    if (base + 3 < n) v3 = cnt[base + 3];
    int s = v0 + v1 + v2 + v3;
    sh[t] = s;
    __syncthreads();
    for (int off = 1; off < 256; off <<= 1) {
        int add = (t >= off) ? sh[t - off] : 0;
        __syncthreads();
        sh[t] += add;
        __syncthreads();
    }
    int excl = sh[t] - s;
    if (t == 255) bsum[blockIdx.x] = sh[255];
    int p = excl;
    if (base + 0 < n) row_start[base + 0] = p; p += v0;
    if (base + 1 < n) row_start[base + 1] = p; p += v1;
    if (base + 2 < n) row_start[base + 2] = p; p += v2;
    if (base + 3 < n) row_start[base + 3] = p;
}

__global__ void scan2_kernel(const int* __restrict__ bsum, int* __restrict__ boff,
                             int* __restrict__ row_start, int nb, int n) {
    if (threadIdx.x == 0 && blockIdx.x == 0) {
        int run = 0;
        for (int b = 0; b < nb; b++) { boff[b] = run; run += bsum[b]; }
        row_start[n] = run;   // == E
    }
}

__global__ __launch_bounds__(256) void scan3_kernel(int* __restrict__ row_start,
                                                    int* __restrict__ cursor,
                                                    const int* __restrict__ boff, int n) {
    int t = threadIdx.x;
    int base = blockIdx.x * 1024 + t * 4;
    int off = boff[blockIdx.x];
#pragma unroll
    for (int i = 0; i < 4; i++) {
        int idx = base + i;
        if (idx < n) {
            int v = row_start[idx] + off;
            row_start[idx] = v;
            cursor[idx] = v;
        }
    }
}

__global__ void fill_kernel(const int* __restrict__ ei, int E, int* __restrict__ cursor,
                            const float* __restrict__ dinv, int* __restrict__ csr_src,
                            float* __restrict__ csr_coef) {
    int e = blockIdx.x * 256 + threadIdx.x;
    if (e < E) {
        int s = ei[e], d = ei[E + e];
        int pos = atomicAdd(&cursor[d], 1);
        csr_src[pos] = s;
        csr_coef[pos] = dinv[s] * dinv[d];
    }
}

// ---------------------------------------------------------------------------
// W [128][128] fp32 row-major ([k][col]) -> WT bf16 [col][k]
// ---------------------------------------------------------------------------
__global__ void wconv_kernel(const float* __restrict__ W, u16* __restrict__ WT) {
    int i = blockIdx.x * 256 + threadIdx.x;   // 0..16383
    int k = i >> 7, col = i & 127;
    WT[col * 128 + k] = f2bf(W[i]);
}

// ---------------------------------------------------------------------------
// out[n x 128] = A[n x 128] @ W[128 x 128] via bf16 MFMA, fp32 accumulate.
// Block: 256 thr (4 waves, 2x2), tile 128x128, K=128 staged once.
// LDS element layout: buf[row*128 + (k ^ ((row&7)<<3))]  (bank-uniform b128 reads)
// ---------------------------------------------------------------------------
__global__ __launch_bounds__(256) void gemm128_mfma(const float* __restrict__ A,
                                                    const u16* __restrict__ WT,
                                                    float* __restrict__ out, int n) {
    __shared__ u16 As[128 * 128];
    __shared__ u16 Bs[128 * 128];
    const int t = threadIdx.x;
    const int r0 = blockIdx.x * 128;

    // stage WT (bf16, [col][k] linear) -> Bs swizzled
#pragma unroll
    for (int j = 0; j < 8; j++) {
        int f = t + j * 256;            // u16x8 id, 2048 total
        int col = f >> 4;
        int k0 = (f & 15) * 8;
        u16x8 v = *(const u16x8*)(WT + col * 128 + k0);
        *(u16x8*)&Bs[col * 128 + (k0 ^ ((col & 7) << 3))] = v;
    }
    // stage A (fp32 -> bf16) -> As swizzled
#pragma unroll
    for (int j = 0; j < 16; j++) {
        int f = t + j * 256;            // float4 id, 4096 total
        int row = f >> 5;
        int k0 = (f & 31) * 4;
        float4 v = make_float4(0.f, 0.f, 0.f, 0.f);
        if (r0 + row < n) v = *(const float4*)(A + (size_t)(r0 + row) * 128 + k0);
        u16x4 b;
        b[0] = f2bf(v.x); b[1] = f2bf(v.y); b[2] = f2bf(v.z); b[3] = f2bf(v.w);
        *(u16x4*)&As[row * 128 + (k0 ^ ((row & 7) << 3))] = b;
    }
    __syncthreads();

    const int w = t >> 6, lane = t & 63;
    const int wr = (w >> 1) * 64;       // wave row offset
    const int wc = (w & 1) * 64;        // wave col offset
    const int lr = lane & 31;
    const int kj = (lane >> 5) * 8;
    const int swz = (lr & 7) << 3;      // (row&7)==(lr&7) for all rows we touch

    f32x16 acc00, acc01, acc10, acc11;
#pragma unroll
    for (int i = 0; i < 16; i++) { acc00[i] = 0.f; acc01[i] = 0.f; acc10[i] = 0.f; acc11[i] = 0.f; }

#pragma unroll
    for (int ks = 0; ks < 8; ks++) {
        int ko = (ks * 16 + kj) ^ swz;
        short8v a0 = *(const short8v*)&As[(wr + lr) * 128 + ko];
        short8v a1 = *(const short8v*)&As[(wr + 32 + lr) * 128 + ko];
        short8v b0 = *(const short8v*)&Bs[(wc + lr) * 128 + ko];
        short8v b1 = *(const short8v*)&Bs[(wc + 32 + lr) * 128 + ko];
        acc00 = __builtin_amdgcn_mfma_f32_32x32x16_bf16(a0, b0, acc00, 0, 0, 0);
        acc01 = __builtin_amdgcn_mfma_f32_32x32x16_bf16(a0, b1, acc01, 0, 0, 0);
        acc10 = __builtin_amdgcn_mfma_f32_32x32x16_bf16(a1, b0, acc10, 0, 0, 0);
        acc11 = __builtin_amdgcn_mfma_f32_32x32x16_bf16(a1, b1, acc11, 0, 0, 0);
    }

    // C/D layout: col = lane&31, row = (reg&3) + 8*(reg>>2) + 4*(lane>>5)
    const int rb = (lane >> 5) * 4;
#pragma unroll
    for (int r = 0; r < 16; r++) {
        int rr = (r & 3) + 8 * (r >> 2) + rb;
        int row0 = r0 + wr + rr;
        int row1 = r0 + wr + 32 + rr;
        if (row0 < n) {
            out[(size_t)row0 * 128 + wc + lr]      = acc00[r];
            out[(size_t)row0 * 128 + wc + 32 + lr] = acc01[r];
        }
        if (row1 < n) {
            out[(size_t)row1 * 128 + wc + lr]      = acc10[r];
            out[(size_t)row1 * 128 + wc + 32 + lr] = acc11[r];
        }
    }
}

// ---------------------------------------------------------------------------
// out[n x 40] = A[n x 128] @ W[128 x 40], fp32 register-tiled
// ---------------------------------------------------------------------------
__global__ __launch_bounds__(256) void gemm40_kernel(const float* __restrict__ A,
                                                     const float* __restrict__ W,
                                                     float* __restrict__ out, int n) {
    __shared__ float wt[40][132];
    const int t = threadIdx.x;
    for (int i = t; i < 5120; i += 256) {
        int k = i / 40, c = i % 40;
        wt[c][k] = W[i];
    }
    __syncthreads();

    const int tx = t & 7;
    const int ty = t >> 3;
    const int r0 = blockIdx.x * 128 + ty * 4;
    const int c0 = tx * 5;

    bool rv[4];
#pragma unroll
    for (int i = 0; i < 4; i++) rv[i] = (r0 + i) < n;

    float acc[4][5];
#pragma unroll
    for (int i = 0; i < 4; i++)
#pragma unroll
        for (int j = 0; j < 5; j++) acc[i][j] = 0.f;

#pragma unroll 4
    for (int kq = 0; kq < 32; kq++) {
        float4 a[4];
#pragma unroll
        for (int i = 0; i < 4; i++)
            a[i] = rv[i] ? *(const float4*)(A + (size_t)(r0 + i) * 128 + kq * 4)
                         : make_float4(0.f, 0.f, 0.f, 0.f);
        float4 w[5];
#pragma unroll
        for (int j = 0; j < 5; j++)
            w[j] = *(const float4*)&wt[c0 + j][kq * 4];
#pragma unroll
        for (int i = 0; i < 4; i++) {
            const float* pa = (const float*)&a[i];
#pragma unroll
            for (int j = 0; j < 5; j++) {
                const float* pw = (const float*)&w[j];
                acc[i][j] = fmaf(pa[0], pw[0], acc[i][j]);
                acc[i][j] = fmaf(pa[1], pw[1], acc[i][j]);
                acc[i][j] = fmaf(pa[2], pw[2], acc[i][j]);
                acc[i][j] = fmaf(pa[3], pw[3], acc[i][j]);
            }
        }
    }

#pragma unroll
    for (int i = 0; i < 4; i++) {
        if (rv[i]) {
#pragma unroll
            for (int j = 0; j < 5; j++)
                out[(size_t)(r0 + i) * 40 + c0 + j] = acc[i][j];
        }
    }
}

// pull aggregation, 128 features, float4: 8 nodes / 256-thr block
__global__ __launch_bounds__(256) void agg128_kernel(const float* __restrict__ hw,
                                                     const float* __restrict__ dinv,
                                                     const int* __restrict__ row_start,
                                                     const int* __restrict__ csr_src,
                                                     const float* __restrict__ csr_coef,
                                                     const float* __restrict__ bias,
                                                     float* __restrict__ out, int n,
                                                     int do_relu) {
    int t = threadIdx.x;
    int node = blockIdx.x * 8 + (t >> 5);
    int f = t & 31;
    if (node >= n) return;
    const float4* hw4 = (const float4*)hw;
    float di = dinv[node];
    float s2 = di * di;
    float4 v = hw4[(size_t)node * 32 + f];
    float4 acc = make_float4(v.x * s2, v.y * s2, v.z * s2, v.w * s2);
    int e0 = row_start[node], e1 = row_start[node + 1];
    for (int e = e0; e < e1; e++) {
        int s = csr_src[e];
        float c = csr_coef[e];
        float4 u = hw4[(size_t)s * 32 + f];
        acc.x = fmaf(c, u.x, acc.x);
        acc.y = fmaf(c, u.y, acc.y);
        acc.z = fmaf(c, u.z, acc.z);
        acc.w = fmaf(c, u.w, acc.w);
    }
    float4 b4 = ((const float4*)bias)[f];
    acc.x += b4.x; acc.y += b4.y; acc.z += b4.z; acc.w += b4.w;
    if (do_relu) {
        acc.x = fmaxf(acc.x, 0.f); acc.y = fmaxf(acc.y, 0.f);
        acc.z = fmaxf(acc.z, 0.f); acc.w = fmaxf(acc.w, 0.f);
    }
    ((float4*)out)[(size_t)node * 32 + f] = acc;
}

// pull aggregation, 40 features: 8 nodes / 320-thr block
__global__ __launch_bounds__(320) void agg40_kernel(const float* __restrict__ hw,
                                                    const float* __restrict__ dinv,
                                                    const int* __restrict__ row_start,
                                                    const int* __restrict__ csr_src,
                                                    const float* __restrict__ csr_coef,
                                                    const float* __restrict__ bias,
                                                    float* __restrict__ out, int n) {
    int t = threadIdx.x;
    int node = blockIdx.x * 8 + t / 40;
    int f = t % 40;
    if (node >= n) return;
    float di = dinv[node];
    float acc = di * di * hw[(size_t)node * 40 + f];
    int e0 = row_start[node], e1 = row_start[node + 1];
    for (int e = e0; e < e1; e++) {
        int s = csr_src[e];
        float c = csr_coef[e];
        acc = fmaf(c, hw[(size_t)s * 40 + f], acc);
    }
    out[(size_t)node * 40 + f] = acc + bias[f];
}

extern "C" void kernel_launch(void* const* d_in, const int* in_sizes, int n_in,
                              void* d_out, int out_size, void* d_ws, size_t ws_size,
                              hipStream_t stream) {
    const float* x  = (const float*)d_in[0];
    const int*   ei = (const int*)d_in[1];
    const float* W1 = (const float*)d_in[2];
    const float* b1 = (const float*)d_in[3];
    const float* W2 = (const float*)d_in[4];
    const float* b2 = (const float*)d_in[5];
    const float* W3 = (const float*)d_in[6];
    const float* b3 = (const float*)d_in[7];
    float* out = (float*)d_out;

    const int n = in_sizes[0] / 128;   // 170000
    const int E = in_sizes[1] / 2;     // 1200000

    // workspace carve (256B aligned)
    char* p = (char*)d_ws;
    auto alloc = [&](size_t bytes) { void* r = (void*)p; p += (bytes + 255) & ~(size_t)255; return r; };
    int*   cnt       = (int*)alloc((size_t)n * 4);
    int*   row_start = (int*)alloc((size_t)(n + 1) * 4);
    int*   cursor    = (int*)alloc((size_t)n * 4);
    int*   bsum      = (int*)alloc(1024 * 4);
    int*   boff      = (int*)alloc(1024 * 4);
    float* dinv      = (float*)alloc((size_t)n * 4);
    int*   csr_src   = (int*)alloc((size_t)E * 4);
    float* csr_coef  = (float*)alloc((size_t)E * 4);
    float* bufA      = (float*)alloc((size_t)n * 128 * 4);
    float* bufB      = (float*)alloc((size_t)n * 128 * 4);
    u16*   wt1       = (u16*)alloc(16384 * 2);
    u16*   wt2       = (u16*)alloc(16384 * 2);

    // --- weight convert (independent of CSR build) ---
    wconv_kernel<<<64, 256, 0, stream>>>(W1, wt1);
    wconv_kernel<<<64, 256, 0, stream>>>(W2, wt2);

    // --- CSR build ---
    hipMemsetAsync(cnt, 0, (size_t)n * 4, stream);
    count_kernel<<<(E + 255) / 256, 256, 0, stream>>>(ei, E, cnt);
    dinv_kernel<<<(n + 255) / 256, 256, 0, stream>>>(cnt, dinv, n);
    int nb = (n + 1023) / 1024;
    scan1_kernel<<<nb, 256, 0, stream>>>(cnt, row_start, bsum, n);
    scan2_kernel<<<1, 64, 0, stream>>>(bsum, boff, row_start, nb, n);
    scan3_kernel<<<nb, 256, 0, stream>>>(row_start, cursor, boff, n);
    fill_kernel<<<(E + 255) / 256, 256, 0, stream>>>(ei, E, cursor, dinv, csr_src, csr_coef);

    const int gblk = (n + 127) / 128;

    // --- layer 1 ---
    gemm128_mfma<<<gblk, 256, 0, stream>>>(x, wt1, bufA, n);
    agg128_kernel<<<(n + 7) / 8, 256, 0, stream>>>(bufA, dinv, row_start, csr_src, csr_coef, b1, bufB, n, 1);
    // --- layer 2 ---
    gemm128_mfma<<<gblk, 256, 0, stream>>>(bufB, wt2, bufA, n);
    agg128_kernel<<<(n + 7) / 8, 256, 0, stream>>>(bufA, dinv, row_start, csr_src, csr_coef, b2, bufB, n, 1);
    // --- layer 3 (W first: A(hW3) == (Ah)W3, aggregate only 40 features) ---
    gemm40_kernel<<<(n + 127) / 128, 256, 0, stream>>>(bufB, W3, bufA, n);
    agg40_kernel<<<(n + 7) / 8, 320, 0, stream>>>(bufA, dinv, row_start, csr_src, csr_coef, b3, out, n);
}

// Round 4
// 586.232 us; speedup vs baseline: 1.9865x; 1.2858x over previous
//
#include <hip/hip_runtime.h>

typedef unsigned short u16;
typedef u16   u16x8  __attribute__((ext_vector_type(8)));
typedef u16   u16x4  __attribute__((ext_vector_type(4)));
typedef short short8v __attribute__((ext_vector_type(8)));
typedef float f32x16  __attribute__((ext_vector_type(16)));

__device__ __forceinline__ u16 f2bf(float f) {
    unsigned u = __float_as_uint(f);
    unsigned r = (u + 0x7fffu + ((u >> 16) & 1u)) >> 16;   // round-to-nearest-even
    return (u16)r;
}
__device__ __forceinline__ float bf2f(u16 h) {
    return __uint_as_float(((unsigned)h) << 16);
}

// ---------------------------------------------------------------------------
// CSR build: count -> scan -> fill (csr packed as int2{src, coef_bits})
// ---------------------------------------------------------------------------
__global__ void count_kernel(const int* __restrict__ ei, int E, int* __restrict__ cnt) {
    int e = blockIdx.x * 256 + threadIdx.x;
    if (e < E) atomicAdd(&cnt[ei[E + e]], 1);
}

__global__ void dinv_kernel(const int* __restrict__ cnt, float* __restrict__ dinv, int n) {
    int i = blockIdx.x * 256 + threadIdx.x;
    if (i < n) dinv[i] = rsqrtf((float)(cnt[i] + 1));  // +1 self loop; always > 0
}

__global__ __launch_bounds__(256) void scan1_kernel(const int* __restrict__ cnt,
                                                    int* __restrict__ row_start,
                                                    int* __restrict__ bsum, int n) {
    __shared__ int sh[256];
    int t = threadIdx.x;
    int base = blockIdx.x * 1024 + t * 4;
    int v0 = 0, v1 = 0, v2 = 0, v3 = 0;
    if (base + 0 < n) v0 = cnt[base + 0];
    if (base + 1 < n) v1 = cnt[base + 1];
    if (base + 2 < n) v2 = cnt[base + 2];
    if (base + 3 < n) v3 = cnt[base + 3];
    int s = v0 + v1 + v2 + v3;
    sh[t] = s;
    __syncthreads();
    for (int off = 1; off < 256; off <<= 1) {
        int add = (t >= off) ? sh[t - off] : 0;
        __syncthreads();
        sh[t] += add;
        __syncthreads();
    }
    int excl = sh[t] - s;
    if (t == 255) bsum[blockIdx.x] = sh[255];
    int p = excl;
    if (base + 0 < n) row_start[base + 0] = p; p += v0;
    if (base + 1 < n) row_start[base + 1] = p; p += v1;
    if (base + 2 < n) row_start[base + 2] = p; p += v2;
    if (base + 3 < n) row_start[base + 3] = p;
}

// parallel scan of block sums (nb <= 256 guaranteed: n=170000 -> nb=167)
__global__ __launch_bounds__(256) void scan2_kernel(const int* __restrict__ bsum,
                                                    int* __restrict__ boff,
                                                    int* __restrict__ row_start, int nb, int n) {
    __shared__ int sh[256];
    int t = threadIdx.x;
    int v = (t < nb) ? bsum[t] : 0;
    sh[t] = v;
    __syncthreads();
    for (int off = 1; off < 256; off <<= 1) {
        int add = (t >= off) ? sh[t - off] : 0;
        __syncthreads();
        sh[t] += add;
        __syncthreads();
    }
    if (t < nb) boff[t] = sh[t] - v;
    if (t == 255) row_start[n] = sh[255];
}

__global__ __launch_bounds__(256) void scan3_kernel(int* __restrict__ row_start,
                                                    int* __restrict__ cursor,
                                                    const int* __restrict__ boff, int n) {
    int t = threadIdx.x;
    int base = blockIdx.x * 1024 + t * 4;
    int off = boff[blockIdx.x];
#pragma unroll
    for (int i = 0; i < 4; i++) {
        int idx = base + i;
        if (idx < n) {
            int v = row_start[idx] + off;
            row_start[idx] = v;
            cursor[idx] = v;
        }
    }
}

__global__ void fill_kernel(const int* __restrict__ ei, int E, int* __restrict__ cursor,
                            const float* __restrict__ dinv, int2* __restrict__ csr) {
    int e = blockIdx.x * 256 + threadIdx.x;
    if (e < E) {
        int s = ei[e], d = ei[E + e];
        int pos = atomicAdd(&cursor[d], 1);
        csr[pos] = make_int2(s, __float_as_int(dinv[s] * dinv[d]));
    }
}

// ---------------------------------------------------------------------------
// W [128][128] fp32 row-major ([k][col]) -> WT bf16 [col][k]
// ---------------------------------------------------------------------------
__global__ void wconv_kernel(const float* __restrict__ W, u16* __restrict__ WT) {
    int i = blockIdx.x * 256 + threadIdx.x;   // 0..16383
    int k = i >> 7, col = i & 127;
    WT[col * 128 + k] = f2bf(W[i]);
}

// ---------------------------------------------------------------------------
// out[n x 128](bf16) = A[n x 128] @ W[128 x 128] via bf16 MFMA, fp32 accum.
// A is fp32 (layer 1) or bf16 (layer 2), selected by template.
// LDS layout: buf[row*128 + (k ^ ((row&7)<<3))]
// ---------------------------------------------------------------------------
template <bool ABF>
__global__ __launch_bounds__(256) void gemm128_mfma(const void* __restrict__ Ap,
                                                    const u16* __restrict__ WT,
                                                    u16* __restrict__ out, int n) {
    __shared__ u16 As[128 * 128];
    __shared__ u16 Bs[128 * 128];
    const int t = threadIdx.x;
    const int r0 = blockIdx.x * 128;

    // stage WT (bf16 [col][k] linear) -> Bs swizzled
#pragma unroll
    for (int j = 0; j < 8; j++) {
        int f = t + j * 256;            // u16x8 id, 2048 total
        int col = f >> 4;
        int k0 = (f & 15) * 8;
        u16x8 v = *(const u16x8*)(WT + col * 128 + k0);
        *(u16x8*)&Bs[col * 128 + (k0 ^ ((col & 7) << 3))] = v;
    }
    // stage A -> As swizzled
    if (ABF) {
        const u16* A = (const u16*)Ap;
#pragma unroll
        for (int j = 0; j < 8; j++) {
            int f = t + j * 256;        // u16x8 id, 2048 total
            int row = f >> 4;
            int k0 = (f & 15) * 8;
            u16x8 v = {0, 0, 0, 0, 0, 0, 0, 0};
            if (r0 + row < n) v = *(const u16x8*)(A + (size_t)(r0 + row) * 128 + k0);
            *(u16x8*)&As[row * 128 + (k0 ^ ((row & 7) << 3))] = v;
        }
    } else {
        const float* A = (const float*)Ap;
#pragma unroll
        for (int j = 0; j < 16; j++) {
            int f = t + j * 256;        // float4 id, 4096 total
            int row = f >> 5;
            int k0 = (f & 31) * 4;
            float4 v = make_float4(0.f, 0.f, 0.f, 0.f);
            if (r0 + row < n) v = *(const float4*)(A + (size_t)(r0 + row) * 128 + k0);
            u16x4 b;
            b[0] = f2bf(v.x); b[1] = f2bf(v.y); b[2] = f2bf(v.z); b[3] = f2bf(v.w);
            *(u16x4*)&As[row * 128 + (k0 ^ ((row & 7) << 3))] = b;
        }
    }
    __syncthreads();

    const int w = t >> 6, lane = t & 63;
    const int wr = (w >> 1) * 64;
    const int wc = (w & 1) * 64;
    const int lr = lane & 31;
    const int kj = (lane >> 5) * 8;
    const int swz = (lr & 7) << 3;

    f32x16 acc00, acc01, acc10, acc11;
#pragma unroll
    for (int i = 0; i < 16; i++) { acc00[i] = 0.f; acc01[i] = 0.f; acc10[i] = 0.f; acc11[i] = 0.f; }

#pragma unroll
    for (int ks = 0; ks < 8; ks++) {
        int ko = (ks * 16 + kj) ^ swz;
        short8v a0 = *(const short8v*)&As[(wr + lr) * 128 + ko];
        short8v a1 = *(const short8v*)&As[(wr + 32 + lr) * 128 + ko];
        short8v b0 = *(const short8v*)&Bs[(wc + lr) * 128 + ko];
        short8v b1 = *(const short8v*)&Bs[(wc + 32 + lr) * 128 + ko];
        acc00 = __builtin_amdgcn_mfma_f32_32x32x16_bf16(a0, b0, acc00, 0, 0, 0);
        acc01 = __builtin_amdgcn_mfma_f32_32x32x16_bf16(a0, b1, acc01, 0, 0, 0);
        acc10 = __builtin_amdgcn_mfma_f32_32x32x16_bf16(a1, b0, acc10, 0, 0, 0);
        acc11 = __builtin_amdgcn_mfma_f32_32x32x16_bf16(a1, b1, acc11, 0, 0, 0);
    }

    // C/D: col = lane&31, row = (reg&3) + 8*(reg>>2) + 4*(lane>>5)
    const int rb = (lane >> 5) * 4;
#pragma unroll
    for (int r = 0; r < 16; r++) {
        int rr = (r & 3) + 8 * (r >> 2) + rb;
        int row0 = r0 + wr + rr;
        int row1 = r0 + wr + 32 + rr;
        if (row0 < n) {
            out[(size_t)row0 * 128 + wc + lr]      = f2bf(acc00[r]);
            out[(size_t)row0 * 128 + wc + 32 + lr] = f2bf(acc01[r]);
        }
        if (row1 < n) {
            out[(size_t)row1 * 128 + wc + lr]      = f2bf(acc10[r]);
            out[(size_t)row1 * 128 + wc + 32 + lr] = f2bf(acc11[r]);
        }
    }
}

// ---------------------------------------------------------------------------
// out[n x 40](fp32) = A[n x 128](bf16) @ W[128 x 40](fp32), fp32 accum
// ---------------------------------------------------------------------------
__global__ __launch_bounds__(256) void gemm40_bf16(const u16* __restrict__ A,
                                                   const float* __restrict__ W,
                                                   float* __restrict__ out, int n) {
    __shared__ float wt[40][132];
    const int t = threadIdx.x;
    for (int i = t; i < 5120; i += 256) {
        int k = i / 40, c = i % 40;
        wt[c][k] = W[i];
    }
    __syncthreads();

    const int tx = t & 7;
    const int ty = t >> 3;
    const int r0 = blockIdx.x * 128 + ty * 4;
    const int c0 = tx * 5;

    bool rv[4];
#pragma unroll
    for (int i = 0; i < 4; i++) rv[i] = (r0 + i) < n;

    float acc[4][5];
#pragma unroll
    for (int i = 0; i < 4; i++)
#pragma unroll
        for (int j = 0; j < 5; j++) acc[i][j] = 0.f;

#pragma unroll 4
    for (int kq = 0; kq < 32; kq++) {
        float a[4][4];
#pragma unroll
        for (int i = 0; i < 4; i++) {
            if (rv[i]) {
                u16x4 h = *(const u16x4*)(A + (size_t)(r0 + i) * 128 + kq * 4);
                a[i][0] = bf2f(h[0]); a[i][1] = bf2f(h[1]);
                a[i][2] = bf2f(h[2]); a[i][3] = bf2f(h[3]);
            } else {
                a[i][0] = a[i][1] = a[i][2] = a[i][3] = 0.f;
            }
        }
        float4 w[5];
#pragma unroll
        for (int j = 0; j < 5; j++)
            w[j] = *(const float4*)&wt[c0 + j][kq * 4];
#pragma unroll
        for (int i = 0; i < 4; i++) {
#pragma unroll
            for (int j = 0; j < 5; j++) {
                const float* pw = (const float*)&w[j];
                acc[i][j] = fmaf(a[i][0], pw[0], acc[i][j]);
                acc[i][j] = fmaf(a[i][1], pw[1], acc[i][j]);
                acc[i][j] = fmaf(a[i][2], pw[2], acc[i][j]);
                acc[i][j] = fmaf(a[i][3], pw[3], acc[i][j]);
            }
        }
    }

#pragma unroll
    for (int i = 0; i < 4; i++) {
        if (rv[i]) {
#pragma unroll
            for (int j = 0; j < 5; j++)
                out[(size_t)(r0 + i) * 40 + c0 + j] = acc[i][j];
        }
    }
}

// ---------------------------------------------------------------------------
// pull aggregation, 128 bf16 features: 16 nodes / 256-thr block,
// 16 lanes per node each owning 8 consecutive bf16 (16B loads).
// ---------------------------------------------------------------------------
__global__ __launch_bounds__(256) void agg128_bf16(const u16* __restrict__ hw,
                                                   const float* __restrict__ dinv,
                                                   const int* __restrict__ row_start,
                                                   const int2* __restrict__ csr,
                                                   const float* __restrict__ bias,
                                                   u16* __restrict__ out, int n,
                                                   int do_relu) {
    int t = threadIdx.x;
    int node = blockIdx.x * 16 + (t >> 4);
    int f = t & 15;
    if (node >= n) return;
    const u16x8* hw8 = (const u16x8*)hw;   // row = 16 chunks of 8 bf16
    float di = dinv[node];
    float s2 = di * di;
    u16x8 v = hw8[(size_t)node * 16 + f];
    float acc[8];
#pragma unroll
    for (int j = 0; j < 8; j++) acc[j] = bf2f(v[j]) * s2;

    int e0 = row_start[node], e1 = row_start[node + 1];
    int e = e0;
    for (; e + 1 < e1; e += 2) {
        int2 p0 = csr[e], p1 = csr[e + 1];
        u16x8 u0 = hw8[(size_t)p0.x * 16 + f];
        u16x8 u1 = hw8[(size_t)p1.x * 16 + f];
        float c0 = __int_as_float(p0.y), c1 = __int_as_float(p1.y);
#pragma unroll
        for (int j = 0; j < 8; j++) acc[j] = fmaf(c0, bf2f(u0[j]), acc[j]);
#pragma unroll
        for (int j = 0; j < 8; j++) acc[j] = fmaf(c1, bf2f(u1[j]), acc[j]);
    }
    if (e < e1) {
        int2 p0 = csr[e];
        u16x8 u0 = hw8[(size_t)p0.x * 16 + f];
        float c0 = __int_as_float(p0.y);
#pragma unroll
        for (int j = 0; j < 8; j++) acc[j] = fmaf(c0, bf2f(u0[j]), acc[j]);
    }

    const float4* b4 = (const float4*)bias;
    float4 ba = b4[f * 2], bb = b4[f * 2 + 1];
    float bv[8] = {ba.x, ba.y, ba.z, ba.w, bb.x, bb.y, bb.z, bb.w};
    u16x8 o;
#pragma unroll
    for (int j = 0; j < 8; j++) {
        float r = acc[j] + bv[j];
        if (do_relu) r = fmaxf(r, 0.f);
        o[j] = f2bf(r);
    }
    *((u16x8*)out + (size_t)node * 16 + f) = o;
}

// pull aggregation, 40 fp32 features: 8 nodes / 320-thr block
__global__ __launch_bounds__(320) void agg40_kernel(const float* __restrict__ hw,
                                                    const float* __restrict__ dinv,
                                                    const int* __restrict__ row_start,
                                                    const int2* __restrict__ csr,
                                                    const float* __restrict__ bias,
                                                    float* __restrict__ out, int n) {
    int t = threadIdx.x;
    int node = blockIdx.x * 8 + t / 40;
    int f = t % 40;
    if (node >= n) return;
    float di = dinv[node];
    float acc = di * di * hw[(size_t)node * 40 + f];
    int e0 = row_start[node], e1 = row_start[node + 1];
    int e = e0;
    for (; e + 1 < e1; e += 2) {
        int2 p0 = csr[e], p1 = csr[e + 1];
        float v0 = hw[(size_t)p0.x * 40 + f];
        float v1 = hw[(size_t)p1.x * 40 + f];
        acc = fmaf(__int_as_float(p0.y), v0, acc);
        acc = fmaf(__int_as_float(p1.y), v1, acc);
    }
    if (e < e1) {
        int2 p0 = csr[e];
        acc = fmaf(__int_as_float(p0.y), hw[(size_t)p0.x * 40 + f], acc);
    }
    out[(size_t)node * 40 + f] = acc + bias[f];
}

extern "C" void kernel_launch(void* const* d_in, const int* in_sizes, int n_in,
                              void* d_out, int out_size, void* d_ws, size_t ws_size,
                              hipStream_t stream) {
    const float* x  = (const float*)d_in[0];
    const int*   ei = (const int*)d_in[1];
    const float* W1 = (const float*)d_in[2];
    const float* b1 = (const float*)d_in[3];
    const float* W2 = (const float*)d_in[4];
    const float* b2 = (const float*)d_in[5];
    const float* W3 = (const float*)d_in[6];
    const float* b3 = (const float*)d_in[7];
    float* out = (float*)d_out;

    const int n = in_sizes[0] / 128;   // 170000
    const int E = in_sizes[1] / 2;     // 1200000

    // workspace carve (256B aligned)
    char* p = (char*)d_ws;
    auto alloc = [&](size_t bytes) { void* r = (void*)p; p += (bytes + 255) & ~(size_t)255; return r; };
    int*   cnt       = (int*)alloc((size_t)n * 4);
    int*   row_start = (int*)alloc((size_t)(n + 1) * 4);
    int*   cursor    = (int*)alloc((size_t)n * 4);
    int*   bsum      = (int*)alloc(1024 * 4);
    int*   boff      = (int*)alloc(1024 * 4);
    float* dinv      = (float*)alloc((size_t)n * 4);
    int2*  csr       = (int2*)alloc((size_t)E * 8);
    u16*   bufG      = (u16*)alloc((size_t)n * 128 * 2);   // gemm outputs (bf16)
    u16*   bufH      = (u16*)alloc((size_t)n * 128 * 2);   // agg outputs (bf16)
    float* buf40     = (float*)alloc((size_t)n * 40 * 4);  // layer-3 gemm out (fp32)
    u16*   wt1       = (u16*)alloc(16384 * 2);
    u16*   wt2       = (u16*)alloc(16384 * 2);

    // --- weight convert ---
    wconv_kernel<<<64, 256, 0, stream>>>(W1, wt1);
    wconv_kernel<<<64, 256, 0, stream>>>(W2, wt2);

    // --- CSR build ---
    hipMemsetAsync(cnt, 0, (size_t)n * 4, stream);
    count_kernel<<<(E + 255) / 256, 256, 0, stream>>>(ei, E, cnt);
    dinv_kernel<<<(n + 255) / 256, 256, 0, stream>>>(cnt, dinv, n);
    int nb = (n + 1023) / 1024;
    scan1_kernel<<<nb, 256, 0, stream>>>(cnt, row_start, bsum, n);
    scan2_kernel<<<1, 256, 0, stream>>>(bsum, boff, row_start, nb, n);
    scan3_kernel<<<nb, 256, 0, stream>>>(row_start, cursor, boff, n);
    fill_kernel<<<(E + 255) / 256, 256, 0, stream>>>(ei, E, cursor, dinv, csr);

    const int gblk = (n + 127) / 128;

    // --- layer 1 (A fp32) ---
    gemm128_mfma<false><<<gblk, 256, 0, stream>>>(x, wt1, bufG, n);
    agg128_bf16<<<(n + 15) / 16, 256, 0, stream>>>(bufG, dinv, row_start, csr, b1, bufH, n, 1);
    // --- layer 2 (A bf16) ---
    gemm128_mfma<true><<<gblk, 256, 0, stream>>>(bufH, wt2, bufG, n);
    agg128_bf16<<<(n + 15) / 16, 256, 0, stream>>>(bufG, dinv, row_start, csr, b2, bufH, n, 1);
    // --- layer 3 (W first: A(hW3) == (Ah)W3, aggregate only 40 features) ---
    gemm40_bf16<<<(n + 127) / 128, 256, 0, stream>>>(bufH, W3, buf40, n);
    agg40_kernel<<<(n + 7) / 8, 320, 0, stream>>>(buf40, dinv, row_start, csr, b3, out, n);
}

// Round 5
// 582.863 us; speedup vs baseline: 1.9980x; 1.0058x over previous
//
#include <hip/hip_runtime.h>

typedef unsigned short u16;
typedef u16   u16x8  __attribute__((ext_vector_type(8)));
typedef u16   u16x4  __attribute__((ext_vector_type(4)));
typedef u16   u16x2  __attribute__((ext_vector_type(2)));
typedef short short8v __attribute__((ext_vector_type(8)));
typedef float f32x16  __attribute__((ext_vector_type(16)));

__device__ __forceinline__ u16 f2bf(float f) {
    unsigned u = __float_as_uint(f);
    unsigned r = (u + 0x7fffu + ((u >> 16) & 1u)) >> 16;   // round-to-nearest-even
    return (u16)r;
}
__device__ __forceinline__ float bf2f(u16 h) {
    return __uint_as_float(((unsigned)h) << 16);
}

// ---------------------------------------------------------------------------
// CSR build: count -> scan (+dinv) -> fill (csr packed as int2{src, coef_bits})
// ---------------------------------------------------------------------------
__global__ void count_kernel(const int* __restrict__ ei, int E, int* __restrict__ cnt) {
    int e = blockIdx.x * 256 + threadIdx.x;
    if (e < E) atomicAdd(&cnt[ei[E + e]], 1);
}

// scan of cnt + dinv computation fused
__global__ __launch_bounds__(256) void scan1_kernel(const int* __restrict__ cnt,
                                                    int* __restrict__ row_start,
                                                    int* __restrict__ bsum,
                                                    float* __restrict__ dinv, int n) {
    __shared__ int sh[256];
    int t = threadIdx.x;
    int base = blockIdx.x * 1024 + t * 4;
    int v0 = 0, v1 = 0, v2 = 0, v3 = 0;
    if (base + 0 < n) { v0 = cnt[base + 0]; dinv[base + 0] = rsqrtf((float)(v0 + 1)); }
    if (base + 1 < n) { v1 = cnt[base + 1]; dinv[base + 1] = rsqrtf((float)(v1 + 1)); }
    if (base + 2 < n) { v2 = cnt[base + 2]; dinv[base + 2] = rsqrtf((float)(v2 + 1)); }
    if (base + 3 < n) { v3 = cnt[base + 3]; dinv[base + 3] = rsqrtf((float)(v3 + 1)); }
    int s = v0 + v1 + v2 + v3;
    sh[t] = s;
    __syncthreads();
    for (int off = 1; off < 256; off <<= 1) {
        int add = (t >= off) ? sh[t - off] : 0;
        __syncthreads();
        sh[t] += add;
        __syncthreads();
    }
    int excl = sh[t] - s;
    if (t == 255) bsum[blockIdx.x] = sh[255];
    int p = excl;
    if (base + 0 < n) row_start[base + 0] = p; p += v0;
    if (base + 1 < n) row_start[base + 1] = p; p += v1;
    if (base + 2 < n) row_start[base + 2] = p; p += v2;
    if (base + 3 < n) row_start[base + 3] = p;
}

// parallel scan of block sums (nb <= 256: n=170000 -> nb=167)
__global__ __launch_bounds__(256) void scan2_kernel(const int* __restrict__ bsum,
                                                    int* __restrict__ boff,
                                                    int* __restrict__ row_start, int nb, int n) {
    __shared__ int sh[256];
    int t = threadIdx.x;
    int v = (t < nb) ? bsum[t] : 0;
    sh[t] = v;
    __syncthreads();
    for (int off = 1; off < 256; off <<= 1) {
        int add = (t >= off) ? sh[t - off] : 0;
        __syncthreads();
        sh[t] += add;
        __syncthreads();
    }
    if (t < nb) boff[t] = sh[t] - v;
    if (t == 255) row_start[n] = sh[255];
}

__global__ __launch_bounds__(256) void scan3_kernel(int* __restrict__ row_start,
                                                    int* __restrict__ cursor,
                                                    const int* __restrict__ boff, int n) {
    int t = threadIdx.x;
    int base = blockIdx.x * 1024 + t * 4;
    int off = boff[blockIdx.x];
#pragma unroll
    for (int i = 0; i < 4; i++) {
        int idx = base + i;
        if (idx < n) {
            int v = row_start[idx] + off;
            row_start[idx] = v;
            cursor[idx] = v;
        }
    }
}

__global__ void fill_kernel(const int* __restrict__ ei, int E, int* __restrict__ cursor,
                            const float* __restrict__ dinv, int2* __restrict__ csr) {
    int e = blockIdx.x * 256 + threadIdx.x;
    if (e < E) {
        int s = ei[e], d = ei[E + e];
        int pos = atomicAdd(&cursor[d], 1);
        csr[pos] = make_int2(s, __float_as_int(dinv[s] * dinv[d]));
    }
}

// ---------------------------------------------------------------------------
// W1,W2 [128][128] fp32 row-major ([k][col]) -> bf16 [col][k], one launch
// ---------------------------------------------------------------------------
__global__ void wconv2_kernel(const float* __restrict__ W1, const float* __restrict__ W2,
                              u16* __restrict__ WT1, u16* __restrict__ WT2) {
    int i = blockIdx.x * 256 + threadIdx.x;   // 0..32767
    const float* W = (i < 16384) ? W1 : W2;
    u16* WT = (i < 16384) ? WT1 : WT2;
    int j = i & 16383;
    int k = j >> 7, col = j & 127;
    WT[col * 128 + k] = f2bf(W[j]);
}

// ---------------------------------------------------------------------------
// out[n x 128](bf16) = A[n x 128] @ W[128 x 128] via bf16 MFMA, fp32 accum.
// A fp32 (layer 1) or bf16 (layer 2). LDS: buf[row*128 + (k ^ ((row&7)<<3))]
// ---------------------------------------------------------------------------
template <bool ABF>
__global__ __launch_bounds__(256) void gemm128_mfma(const void* __restrict__ Ap,
                                                    const u16* __restrict__ WT,
                                                    u16* __restrict__ out, int n) {
    __shared__ u16 As[128 * 128];
    __shared__ u16 Bs[128 * 128];
    const int t = threadIdx.x;
    const int r0 = blockIdx.x * 128;

#pragma unroll
    for (int j = 0; j < 8; j++) {
        int f = t + j * 256;
        int col = f >> 4;
        int k0 = (f & 15) * 8;
        u16x8 v = *(const u16x8*)(WT + col * 128 + k0);
        *(u16x8*)&Bs[col * 128 + (k0 ^ ((col & 7) << 3))] = v;
    }
    if (ABF) {
        const u16* A = (const u16*)Ap;
#pragma unroll
        for (int j = 0; j < 8; j++) {
            int f = t + j * 256;
            int row = f >> 4;
            int k0 = (f & 15) * 8;
            u16x8 v = {0, 0, 0, 0, 0, 0, 0, 0};
            if (r0 + row < n) v = *(const u16x8*)(A + (size_t)(r0 + row) * 128 + k0);
            *(u16x8*)&As[row * 128 + (k0 ^ ((row & 7) << 3))] = v;
        }
    } else {
        const float* A = (const float*)Ap;
#pragma unroll
        for (int j = 0; j < 16; j++) {
            int f = t + j * 256;
            int row = f >> 5;
            int k0 = (f & 31) * 4;
            float4 v = make_float4(0.f, 0.f, 0.f, 0.f);
            if (r0 + row < n) v = *(const float4*)(A + (size_t)(r0 + row) * 128 + k0);
            u16x4 b;
            b[0] = f2bf(v.x); b[1] = f2bf(v.y); b[2] = f2bf(v.z); b[3] = f2bf(v.w);
            *(u16x4*)&As[row * 128 + (k0 ^ ((row & 7) << 3))] = b;
        }
    }
    __syncthreads();

    const int w = t >> 6, lane = t & 63;
    const int wr = (w >> 1) * 64;
    const int wc = (w & 1) * 64;
    const int lr = lane & 31;
    const int kj = (lane >> 5) * 8;
    const int swz = (lr & 7) << 3;

    f32x16 acc00, acc01, acc10, acc11;
#pragma unroll
    for (int i = 0; i < 16; i++) { acc00[i] = 0.f; acc01[i] = 0.f; acc10[i] = 0.f; acc11[i] = 0.f; }

#pragma unroll
    for (int ks = 0; ks < 8; ks++) {
        int ko = (ks * 16 + kj) ^ swz;
        short8v a0 = *(const short8v*)&As[(wr + lr) * 128 + ko];
        short8v a1 = *(const short8v*)&As[(wr + 32 + lr) * 128 + ko];
        short8v b0 = *(const short8v*)&Bs[(wc + lr) * 128 + ko];
        short8v b1 = *(const short8v*)&Bs[(wc + 32 + lr) * 128 + ko];
        acc00 = __builtin_amdgcn_mfma_f32_32x32x16_bf16(a0, b0, acc00, 0, 0, 0);
        acc01 = __builtin_amdgcn_mfma_f32_32x32x16_bf16(a0, b1, acc01, 0, 0, 0);
        acc10 = __builtin_amdgcn_mfma_f32_32x32x16_bf16(a1, b0, acc10, 0, 0, 0);
        acc11 = __builtin_amdgcn_mfma_f32_32x32x16_bf16(a1, b1, acc11, 0, 0, 0);
    }

    const int rb = (lane >> 5) * 4;
#pragma unroll
    for (int r = 0; r < 16; r++) {
        int rr = (r & 3) + 8 * (r >> 2) + rb;
        int row0 = r0 + wr + rr;
        int row1 = r0 + wr + 32 + rr;
        if (row0 < n) {
            out[(size_t)row0 * 128 + wc + lr]      = f2bf(acc00[r]);
            out[(size_t)row0 * 128 + wc + 32 + lr] = f2bf(acc01[r]);
        }
        if (row1 < n) {
            out[(size_t)row1 * 128 + wc + lr]      = f2bf(acc10[r]);
            out[(size_t)row1 * 128 + wc + 32 + lr] = f2bf(acc11[r]);
        }
    }
}

// ---------------------------------------------------------------------------
// g3[n x 40](bf16) = A[n x 128](bf16) @ W[128 x 40](fp32), fp32 accum.
// Block 320: 32 row-groups x 10 col-groups; 4x4 tile/thread.
// ---------------------------------------------------------------------------
__global__ __launch_bounds__(320) void gemm40_bf16(const u16* __restrict__ A,
                                                   const float* __restrict__ W,
                                                   u16* __restrict__ out, int n) {
    __shared__ float wt[40][132];
    const int t = threadIdx.x;
    for (int i = t; i < 5120; i += 320) {
        int k = i / 40, c = i % 40;
        wt[c][k] = W[i];
    }
    __syncthreads();

    const int tx = t % 10;          // cols 4*tx .. 4*tx+3
    const int ty = t / 10;          // rows 4*ty .. 4*ty+3
    const int r0 = blockIdx.x * 128 + ty * 4;
    const int c0 = tx * 4;

    bool rv[4];
#pragma unroll
    for (int i = 0; i < 4; i++) rv[i] = (r0 + i) < n;

    float acc[4][4];
#pragma unroll
    for (int i = 0; i < 4; i++)
#pragma unroll
        for (int j = 0; j < 4; j++) acc[i][j] = 0.f;

#pragma unroll 4
    for (int kq = 0; kq < 32; kq++) {
        float a[4][4];
#pragma unroll
        for (int i = 0; i < 4; i++) {
            if (rv[i]) {
                u16x4 h = *(const u16x4*)(A + (size_t)(r0 + i) * 128 + kq * 4);
                a[i][0] = bf2f(h[0]); a[i][1] = bf2f(h[1]);
                a[i][2] = bf2f(h[2]); a[i][3] = bf2f(h[3]);
            } else {
                a[i][0] = a[i][1] = a[i][2] = a[i][3] = 0.f;
            }
        }
        float4 w[4];
#pragma unroll
        for (int j = 0; j < 4; j++)
            w[j] = *(const float4*)&wt[c0 + j][kq * 4];
#pragma unroll
        for (int i = 0; i < 4; i++) {
#pragma unroll
            for (int j = 0; j < 4; j++) {
                const float* pw = (const float*)&w[j];
                acc[i][j] = fmaf(a[i][0], pw[0], acc[i][j]);
                acc[i][j] = fmaf(a[i][1], pw[1], acc[i][j]);
                acc[i][j] = fmaf(a[i][2], pw[2], acc[i][j]);
                acc[i][j] = fmaf(a[i][3], pw[3], acc[i][j]);
            }
        }
    }

#pragma unroll
    for (int i = 0; i < 4; i++) {
        if (rv[i]) {
            u16x4 o;
            o[0] = f2bf(acc[i][0]); o[1] = f2bf(acc[i][1]);
            o[2] = f2bf(acc[i][2]); o[3] = f2bf(acc[i][3]);
            *(u16x4*)(out + (size_t)(r0 + i) * 40 + c0) = o;
        }
    }
}

// ---------------------------------------------------------------------------
// pull aggregation, 128 bf16 features: 16 nodes / 256-thr block,
// 16 lanes per node each owning 8 consecutive bf16 (16B loads), 4-deep unroll.
// ---------------------------------------------------------------------------
__global__ __launch_bounds__(256) void agg128_bf16(const u16* __restrict__ hw,
                                                   const float* __restrict__ dinv,
                                                   const int* __restrict__ row_start,
                                                   const int2* __restrict__ csr,
                                                   const float* __restrict__ bias,
                                                   u16* __restrict__ out, int n,
                                                   int do_relu) {
    int t = threadIdx.x;
    int node = blockIdx.x * 16 + (t >> 4);
    int f = t & 15;
    if (node >= n) return;
    const u16x8* hw8 = (const u16x8*)hw;
    float di = dinv[node];
    float s2 = di * di;
    u16x8 v = hw8[(size_t)node * 16 + f];
    float acc[8];
#pragma unroll
    for (int j = 0; j < 8; j++) acc[j] = bf2f(v[j]) * s2;

    int e0 = row_start[node], e1 = row_start[node + 1];
    int e = e0;
    for (; e + 3 < e1; e += 4) {
        int2 p0 = csr[e], p1 = csr[e + 1], p2 = csr[e + 2], p3 = csr[e + 3];
        u16x8 u0 = hw8[(size_t)p0.x * 16 + f];
        u16x8 u1 = hw8[(size_t)p1.x * 16 + f];
        u16x8 u2 = hw8[(size_t)p2.x * 16 + f];
        u16x8 u3 = hw8[(size_t)p3.x * 16 + f];
        float c0 = __int_as_float(p0.y), c1 = __int_as_float(p1.y);
        float c2 = __int_as_float(p2.y), c3 = __int_as_float(p3.y);
#pragma unroll
        for (int j = 0; j < 8; j++) acc[j] = fmaf(c0, bf2f(u0[j]), acc[j]);
#pragma unroll
        for (int j = 0; j < 8; j++) acc[j] = fmaf(c1, bf2f(u1[j]), acc[j]);
#pragma unroll
        for (int j = 0; j < 8; j++) acc[j] = fmaf(c2, bf2f(u2[j]), acc[j]);
#pragma unroll
        for (int j = 0; j < 8; j++) acc[j] = fmaf(c3, bf2f(u3[j]), acc[j]);
    }
    for (; e + 1 < e1; e += 2) {
        int2 p0 = csr[e], p1 = csr[e + 1];
        u16x8 u0 = hw8[(size_t)p0.x * 16 + f];
        u16x8 u1 = hw8[(size_t)p1.x * 16 + f];
        float c0 = __int_as_float(p0.y), c1 = __int_as_float(p1.y);
#pragma unroll
        for (int j = 0; j < 8; j++) acc[j] = fmaf(c0, bf2f(u0[j]), acc[j]);
#pragma unroll
        for (int j = 0; j < 8; j++) acc[j] = fmaf(c1, bf2f(u1[j]), acc[j]);
    }
    if (e < e1) {
        int2 p0 = csr[e];
        u16x8 u0 = hw8[(size_t)p0.x * 16 + f];
        float c0 = __int_as_float(p0.y);
#pragma unroll
        for (int j = 0; j < 8; j++) acc[j] = fmaf(c0, bf2f(u0[j]), acc[j]);
    }

    const float4* b4 = (const float4*)bias;
    float4 ba = b4[f * 2], bb = b4[f * 2 + 1];
    float bv[8] = {ba.x, ba.y, ba.z, ba.w, bb.x, bb.y, bb.z, bb.w};
    u16x8 o;
#pragma unroll
    for (int j = 0; j < 8; j++) {
        float r = acc[j] + bv[j];
        if (do_relu) r = fmaxf(r, 0.f);
        o[j] = f2bf(r);
    }
    *((u16x8*)out + (size_t)node * 16 + f) = o;
}

// ---------------------------------------------------------------------------
// final aggregation, 40 bf16 features -> fp32 out.
// Block 320: 16 nodes, 20 lanes/node, 2 features (u16x2 = 4B) per lane.
// ---------------------------------------------------------------------------
__global__ __launch_bounds__(320) void agg40_bf16(const u16* __restrict__ g3,
                                                  const float* __restrict__ dinv,
                                                  const int* __restrict__ row_start,
                                                  const int2* __restrict__ csr,
                                                  const float* __restrict__ bias,
                                                  float* __restrict__ out, int n) {
    int t = threadIdx.x;
    int node = blockIdx.x * 16 + t / 20;
    int fq = t % 20;                    // features 2fq, 2fq+1
    if (node >= n) return;
    float di = dinv[node];
    float s2 = di * di;
    u16x2 v = *(const u16x2*)(g3 + (size_t)node * 40 + fq * 2);
    float a0 = bf2f(v[0]) * s2;
    float a1 = bf2f(v[1]) * s2;

    int e0 = row_start[node], e1 = row_start[node + 1];
    int e = e0;
    for (; e + 3 < e1; e += 4) {
        int2 p0 = csr[e], p1 = csr[e + 1], p2 = csr[e + 2], p3 = csr[e + 3];
        u16x2 u0 = *(const u16x2*)(g3 + (size_t)p0.x * 40 + fq * 2);
        u16x2 u1 = *(const u16x2*)(g3 + (size_t)p1.x * 40 + fq * 2);
        u16x2 u2 = *(const u16x2*)(g3 + (size_t)p2.x * 40 + fq * 2);
        u16x2 u3 = *(const u16x2*)(g3 + (size_t)p3.x * 40 + fq * 2);
        float c0 = __int_as_float(p0.y), c1 = __int_as_float(p1.y);
        float c2 = __int_as_float(p2.y), c3 = __int_as_float(p3.y);
        a0 = fmaf(c0, bf2f(u0[0]), a0); a1 = fmaf(c0, bf2f(u0[1]), a1);
        a0 = fmaf(c1, bf2f(u1[0]), a0); a1 = fmaf(c1, bf2f(u1[1]), a1);
        a0 = fmaf(c2, bf2f(u2[0]), a0); a1 = fmaf(c2, bf2f(u2[1]), a1);
        a0 = fmaf(c3, bf2f(u3[0]), a0); a1 = fmaf(c3, bf2f(u3[1]), a1);
    }
    for (; e + 1 < e1; e += 2) {
        int2 p0 = csr[e], p1 = csr[e + 1];
        u16x2 u0 = *(const u16x2*)(g3 + (size_t)p0.x * 40 + fq * 2);
        u16x2 u1 = *(const u16x2*)(g3 + (size_t)p1.x * 40 + fq * 2);
        float c0 = __int_as_float(p0.y), c1 = __int_as_float(p1.y);
        a0 = fmaf(c0, bf2f(u0[0]), a0); a1 = fmaf(c0, bf2f(u0[1]), a1);
        a0 = fmaf(c1, bf2f(u1[0]), a0); a1 = fmaf(c1, bf2f(u1[1]), a1);
    }
    if (e < e1) {
        int2 p0 = csr[e];
        u16x2 u0 = *(const u16x2*)(g3 + (size_t)p0.x * 40 + fq * 2);
        float c0 = __int_as_float(p0.y);
        a0 = fmaf(c0, bf2f(u0[0]), a0); a1 = fmaf(c0, bf2f(u0[1]), a1);
    }

    float2 b2v = *(const float2*)(bias + fq * 2);
    float2 o = make_float2(a0 + b2v.x, a1 + b2v.y);
    *(float2*)(out + (size_t)node * 40 + fq * 2) = o;
}

extern "C" void kernel_launch(void* const* d_in, const int* in_sizes, int n_in,
                              void* d_out, int out_size, void* d_ws, size_t ws_size,
                              hipStream_t stream) {
    const float* x  = (const float*)d_in[0];
    const int*   ei = (const int*)d_in[1];
    const float* W1 = (const float*)d_in[2];
    const float* b1 = (const float*)d_in[3];
    const float* W2 = (const float*)d_in[4];
    const float* b2 = (const float*)d_in[5];
    const float* W3 = (const float*)d_in[6];
    const float* b3 = (const float*)d_in[7];
    float* out = (float*)d_out;

    const int n = in_sizes[0] / 128;   // 170000
    const int E = in_sizes[1] / 2;     // 1200000

    // workspace carve (256B aligned)
    char* p = (char*)d_ws;
    auto alloc = [&](size_t bytes) { void* r = (void*)p; p += (bytes + 255) & ~(size_t)255; return r; };
    int*   cnt       = (int*)alloc((size_t)n * 4);
    int*   row_start = (int*)alloc((size_t)(n + 1) * 4);
    int*   cursor    = (int*)alloc((size_t)n * 4);
    int*   bsum      = (int*)alloc(1024 * 4);
    int*   boff      = (int*)alloc(1024 * 4);
    float* dinv      = (float*)alloc((size_t)n * 4);
    int2*  csr       = (int2*)alloc((size_t)E * 8);
    u16*   bufG      = (u16*)alloc((size_t)n * 128 * 2);   // gemm outputs (bf16)
    u16*   bufH      = (u16*)alloc((size_t)n * 128 * 2);   // agg outputs (bf16)
    u16*   g3b       = (u16*)alloc((size_t)n * 40 * 2);    // layer-3 gemm out (bf16)
    u16*   wt1       = (u16*)alloc(16384 * 2);
    u16*   wt2       = (u16*)alloc(16384 * 2);

    // --- weight convert (one launch) ---
    wconv2_kernel<<<128, 256, 0, stream>>>(W1, W2, wt1, wt2);

    // --- CSR build ---
    hipMemsetAsync(cnt, 0, (size_t)n * 4, stream);
    count_kernel<<<(E + 255) / 256, 256, 0, stream>>>(ei, E, cnt);
    int nb = (n + 1023) / 1024;
    scan1_kernel<<<nb, 256, 0, stream>>>(cnt, row_start, bsum, dinv, n);
    scan2_kernel<<<1, 256, 0, stream>>>(bsum, boff, row_start, nb, n);
    scan3_kernel<<<nb, 256, 0, stream>>>(row_start, cursor, boff, n);
    fill_kernel<<<(E + 255) / 256, 256, 0, stream>>>(ei, E, cursor, dinv, csr);

    const int gblk = (n + 127) / 128;

    // --- layer 1 (A fp32) ---
    gemm128_mfma<false><<<gblk, 256, 0, stream>>>(x, wt1, bufG, n);
    agg128_bf16<<<(n + 15) / 16, 256, 0, stream>>>(bufG, dinv, row_start, csr, b1, bufH, n, 1);
    // --- layer 2 (A bf16) ---
    gemm128_mfma<true><<<gblk, 256, 0, stream>>>(bufH, wt2, bufG, n);
    agg128_bf16<<<(n + 15) / 16, 256, 0, stream>>>(bufG, dinv, row_start, csr, b2, bufH, n, 1);
    // --- layer 3 (W first: A(hW3) == (Ah)W3, aggregate only 40 features) ---
    gemm40_bf16<<<gblk, 320, 0, stream>>>(bufH, W3, g3b, n);
    agg40_bf16<<<(n + 15) / 16, 320, 0, stream>>>(g3b, dinv, row_start, csr, b3, out, n);
}

// Round 6
// 478.327 us; speedup vs baseline: 2.4347x; 1.2185x over previous
//
#include <hip/hip_runtime.h>

typedef unsigned short u16;
typedef u16   u16x8  __attribute__((ext_vector_type(8)));
typedef u16   u16x4  __attribute__((ext_vector_type(4)));
typedef u16   u16x2  __attribute__((ext_vector_type(2)));
typedef short short8v __attribute__((ext_vector_type(8)));
typedef float f32x16  __attribute__((ext_vector_type(16)));

__device__ __forceinline__ u16 f2bf(float f) {
    unsigned u = __float_as_uint(f);
    unsigned r = (u + 0x7fffu + ((u >> 16) & 1u)) >> 16;   // round-to-nearest-even
    return (u16)r;
}
__device__ __forceinline__ float bf2f(u16 h) {
    return __uint_as_float(((unsigned)h) << 16);
}

// ---------------------------------------------------------------------------
// CSR build: count -> scan (+dinv) -> fill (csr packed as int2{src, coef_bits})
// ---------------------------------------------------------------------------
__global__ void count_kernel(const int* __restrict__ ei, int E, int* __restrict__ cnt) {
    int e = blockIdx.x * 256 + threadIdx.x;
    if (e < E) atomicAdd(&cnt[ei[E + e]], 1);
}

__global__ __launch_bounds__(256) void scan1_kernel(const int* __restrict__ cnt,
                                                    int* __restrict__ row_start,
                                                    int* __restrict__ bsum,
                                                    float* __restrict__ dinv, int n) {
    __shared__ int sh[256];
    int t = threadIdx.x;
    int base = blockIdx.x * 1024 + t * 4;
    int v0 = 0, v1 = 0, v2 = 0, v3 = 0;
    if (base + 0 < n) { v0 = cnt[base + 0]; dinv[base + 0] = rsqrtf((float)(v0 + 1)); }
    if (base + 1 < n) { v1 = cnt[base + 1]; dinv[base + 1] = rsqrtf((float)(v1 + 1)); }
    if (base + 2 < n) { v2 = cnt[base + 2]; dinv[base + 2] = rsqrtf((float)(v2 + 1)); }
    if (base + 3 < n) { v3 = cnt[base + 3]; dinv[base + 3] = rsqrtf((float)(v3 + 1)); }
    int s = v0 + v1 + v2 + v3;
    sh[t] = s;
    __syncthreads();
    for (int off = 1; off < 256; off <<= 1) {
        int add = (t >= off) ? sh[t - off] : 0;
        __syncthreads();
        sh[t] += add;
        __syncthreads();
    }
    int excl = sh[t] - s;
    if (t == 255) bsum[blockIdx.x] = sh[255];
    int p = excl;
    if (base + 0 < n) row_start[base + 0] = p; p += v0;
    if (base + 1 < n) row_start[base + 1] = p; p += v1;
    if (base + 2 < n) row_start[base + 2] = p; p += v2;
    if (base + 3 < n) row_start[base + 3] = p;
}

// parallel scan of block sums (nb <= 256: n=170000 -> nb=167)
__global__ __launch_bounds__(256) void scan2_kernel(const int* __restrict__ bsum,
                                                    int* __restrict__ boff,
                                                    int* __restrict__ row_start, int nb, int n) {
    __shared__ int sh[256];
    int t = threadIdx.x;
    int v = (t < nb) ? bsum[t] : 0;
    sh[t] = v;
    __syncthreads();
    for (int off = 1; off < 256; off <<= 1) {
        int add = (t >= off) ? sh[t - off] : 0;
        __syncthreads();
        sh[t] += add;
        __syncthreads();
    }
    if (t < nb) boff[t] = sh[t] - v;
    if (t == 255) row_start[n] = sh[255];
}

__global__ __launch_bounds__(256) void scan3_kernel(int* __restrict__ row_start,
                                                    int* __restrict__ cursor,
                                                    const int* __restrict__ boff, int n) {
    int t = threadIdx.x;
    int base = blockIdx.x * 1024 + t * 4;
    int off = boff[blockIdx.x];
#pragma unroll
    for (int i = 0; i < 4; i++) {
        int idx = base + i;
        if (idx < n) {
            int v = row_start[idx] + off;
            row_start[idx] = v;
            cursor[idx] = v;
        }
    }
}

__global__ void fill_kernel(const int* __restrict__ ei, int E, int* __restrict__ cursor,
                            const float* __restrict__ dinv, int2* __restrict__ csr) {
    int e = blockIdx.x * 256 + threadIdx.x;
    if (e < E) {
        int s = ei[e], d = ei[E + e];
        int pos = atomicAdd(&cursor[d], 1);
        csr[pos] = make_int2(s, __float_as_int(dinv[s] * dinv[d]));
    }
}

// ---------------------------------------------------------------------------
// All weights -> bf16 [col][k] transposed, one launch.
// W1,W2: [128][128] -> 128x128. W3: [128][40] -> padded [64][128] (cols 40+ = 0)
// ---------------------------------------------------------------------------
__global__ void wconv_all(const float* __restrict__ W1, const float* __restrict__ W2,
                          const float* __restrict__ W3,
                          u16* __restrict__ WT1, u16* __restrict__ WT2,
                          u16* __restrict__ WT3) {
    int i = blockIdx.x * 256 + threadIdx.x;   // 0..40959
    if (i < 32768) {
        const float* W = (i < 16384) ? W1 : W2;
        u16* WT = (i < 16384) ? WT1 : WT2;
        int j = i & 16383;
        int k = j >> 7, col = j & 127;
        WT[col * 128 + k] = f2bf(W[j]);
    } else {
        int j = i - 32768;                    // 0..8191
        int col = j >> 7, k = j & 127;        // col 0..63
        WT3[j] = (col < 40) ? f2bf(W3[k * 40 + col]) : (u16)0;
    }
}

// ---------------------------------------------------------------------------
// out[n x 128](bf16) = A[n x 128] @ W[128 x 128] via bf16 MFMA, fp32 accum.
// A fp32 (layer 1) or bf16 (layer 2). LDS: buf[row*128 + (k ^ ((row&7)<<3))]
// ---------------------------------------------------------------------------
template <bool ABF>
__global__ __launch_bounds__(256) void gemm128_mfma(const void* __restrict__ Ap,
                                                    const u16* __restrict__ WT,
                                                    u16* __restrict__ out, int n) {
    __shared__ u16 As[128 * 128];
    __shared__ u16 Bs[128 * 128];
    const int t = threadIdx.x;
    const int r0 = blockIdx.x * 128;

#pragma unroll
    for (int j = 0; j < 8; j++) {
        int f = t + j * 256;
        int col = f >> 4;
        int k0 = (f & 15) * 8;
        u16x8 v = *(const u16x8*)(WT + col * 128 + k0);
        *(u16x8*)&Bs[col * 128 + (k0 ^ ((col & 7) << 3))] = v;
    }
    if (ABF) {
        const u16* A = (const u16*)Ap;
#pragma unroll
        for (int j = 0; j < 8; j++) {
            int f = t + j * 256;
            int row = f >> 4;
            int k0 = (f & 15) * 8;
            u16x8 v = {0, 0, 0, 0, 0, 0, 0, 0};
            if (r0 + row < n) v = *(const u16x8*)(A + (size_t)(r0 + row) * 128 + k0);
            *(u16x8*)&As[row * 128 + (k0 ^ ((row & 7) << 3))] = v;
        }
    } else {
        const float* A = (const float*)Ap;
#pragma unroll
        for (int j = 0; j < 16; j++) {
            int f = t + j * 256;
            int row = f >> 5;
            int k0 = (f & 31) * 4;
            float4 v = make_float4(0.f, 0.f, 0.f, 0.f);
            if (r0 + row < n) v = *(const float4*)(A + (size_t)(r0 + row) * 128 + k0);
            u16x4 b;
            b[0] = f2bf(v.x); b[1] = f2bf(v.y); b[2] = f2bf(v.z); b[3] = f2bf(v.w);
            *(u16x4*)&As[row * 128 + (k0 ^ ((row & 7) << 3))] = b;
        }
    }
    __syncthreads();

    const int w = t >> 6, lane = t & 63;
    const int wr = (w >> 1) * 64;
    const int wc = (w & 1) * 64;
    const int lr = lane & 31;
    const int kj = (lane >> 5) * 8;
    const int swz = (lr & 7) << 3;

    f32x16 acc00, acc01, acc10, acc11;
#pragma unroll
    for (int i = 0; i < 16; i++) { acc00[i] = 0.f; acc01[i] = 0.f; acc10[i] = 0.f; acc11[i] = 0.f; }

#pragma unroll
    for (int ks = 0; ks < 8; ks++) {
        int ko = (ks * 16 + kj) ^ swz;
        short8v a0 = *(const short8v*)&As[(wr + lr) * 128 + ko];
        short8v a1 = *(const short8v*)&As[(wr + 32 + lr) * 128 + ko];
        short8v b0 = *(const short8v*)&Bs[(wc + lr) * 128 + ko];
        short8v b1 = *(const short8v*)&Bs[(wc + 32 + lr) * 128 + ko];
        acc00 = __builtin_amdgcn_mfma_f32_32x32x16_bf16(a0, b0, acc00, 0, 0, 0);
        acc01 = __builtin_amdgcn_mfma_f32_32x32x16_bf16(a0, b1, acc01, 0, 0, 0);
        acc10 = __builtin_amdgcn_mfma_f32_32x32x16_bf16(a1, b0, acc10, 0, 0, 0);
        acc11 = __builtin_amdgcn_mfma_f32_32x32x16_bf16(a1, b1, acc11, 0, 0, 0);
    }

    const int rb = (lane >> 5) * 4;
#pragma unroll
    for (int r = 0; r < 16; r++) {
        int rr = (r & 3) + 8 * (r >> 2) + rb;
        int row0 = r0 + wr + rr;
        int row1 = r0 + wr + 32 + rr;
        if (row0 < n) {
            out[(size_t)row0 * 128 + wc + lr]      = f2bf(acc00[r]);
            out[(size_t)row0 * 128 + wc + 32 + lr] = f2bf(acc01[r]);
        }
        if (row1 < n) {
            out[(size_t)row1 * 128 + wc + lr]      = f2bf(acc10[r]);
            out[(size_t)row1 * 128 + wc + 32 + lr] = f2bf(acc11[r]);
        }
    }
}

// ---------------------------------------------------------------------------
// g3[n x 40](bf16) = A[n x 128](bf16) @ W3pad[128 x 64](bf16) via MFMA.
// Block 256 (4 waves); 128 rows/block, each wave 32 rows x 64 cols.
// Only cols 0..39 written (WT3 cols 40..63 are zero).
// ---------------------------------------------------------------------------
__global__ __launch_bounds__(256) void gemm40_mfma(const u16* __restrict__ A,
                                                   const u16* __restrict__ WT3,
                                                   u16* __restrict__ out, int n) {
    __shared__ u16 As[128 * 128];
    __shared__ u16 Bs[64 * 128];
    const int t = threadIdx.x;
    const int r0 = blockIdx.x * 128;

    // stage WT3 (bf16 [64][128] linear) -> Bs swizzled
#pragma unroll
    for (int j = 0; j < 4; j++) {
        int f = t + j * 256;            // u16x8 id, 1024 total
        int col = f >> 4;
        int k0 = (f & 15) * 8;
        u16x8 v = *(const u16x8*)(WT3 + col * 128 + k0);
        *(u16x8*)&Bs[col * 128 + (k0 ^ ((col & 7) << 3))] = v;
    }
    // stage A (bf16) -> As swizzled
#pragma unroll
    for (int j = 0; j < 8; j++) {
        int f = t + j * 256;
        int row = f >> 4;
        int k0 = (f & 15) * 8;
        u16x8 v = {0, 0, 0, 0, 0, 0, 0, 0};
        if (r0 + row < n) v = *(const u16x8*)(A + (size_t)(r0 + row) * 128 + k0);
        *(u16x8*)&As[row * 128 + (k0 ^ ((row & 7) << 3))] = v;
    }
    __syncthreads();

    const int w = t >> 6, lane = t & 63;
    const int wr = w * 32;              // 4 waves x 32 rows
    const int lr = lane & 31;
    const int kj = (lane >> 5) * 8;
    const int swz = (lr & 7) << 3;

    f32x16 acc0, acc1;
#pragma unroll
    for (int i = 0; i < 16; i++) { acc0[i] = 0.f; acc1[i] = 0.f; }

#pragma unroll
    for (int ks = 0; ks < 8; ks++) {
        int ko = (ks * 16 + kj) ^ swz;
        short8v a  = *(const short8v*)&As[(wr + lr) * 128 + ko];
        short8v b0 = *(const short8v*)&Bs[lr * 128 + ko];
        short8v b1 = *(const short8v*)&Bs[(32 + lr) * 128 + ko];
        acc0 = __builtin_amdgcn_mfma_f32_32x32x16_bf16(a, b0, acc0, 0, 0, 0);
        acc1 = __builtin_amdgcn_mfma_f32_32x32x16_bf16(a, b1, acc1, 0, 0, 0);
    }

    // C/D: col = lane&31, row = (reg&3) + 8*(reg>>2) + 4*(lane>>5)
    const int rb = (lane >> 5) * 4;
#pragma unroll
    for (int r = 0; r < 16; r++) {
        int rr = (r & 3) + 8 * (r >> 2) + rb;
        int row = r0 + wr + rr;
        if (row < n) {
            out[(size_t)row * 40 + lr] = f2bf(acc0[r]);
            if (lr < 8) out[(size_t)row * 40 + 32 + lr] = f2bf(acc1[r]);
        }
    }
}

// ---------------------------------------------------------------------------
// pull aggregation, 128 bf16 features: 16 nodes / 256-thr block,
// 16 lanes per node each owning 8 consecutive bf16 (16B loads), 4-deep unroll.
// ---------------------------------------------------------------------------
__global__ __launch_bounds__(256) void agg128_bf16(const u16* __restrict__ hw,
                                                   const float* __restrict__ dinv,
                                                   const int* __restrict__ row_start,
                                                   const int2* __restrict__ csr,
                                                   const float* __restrict__ bias,
                                                   u16* __restrict__ out, int n,
                                                   int do_relu) {
    int t = threadIdx.x;
    int node = blockIdx.x * 16 + (t >> 4);
    int f = t & 15;
    if (node >= n) return;
    const u16x8* hw8 = (const u16x8*)hw;
    float di = dinv[node];
    float s2 = di * di;
    u16x8 v = hw8[(size_t)node * 16 + f];
    float acc[8];
#pragma unroll
    for (int j = 0; j < 8; j++) acc[j] = bf2f(v[j]) * s2;

    int e0 = row_start[node], e1 = row_start[node + 1];
    int e = e0;
    for (; e + 3 < e1; e += 4) {
        int2 p0 = csr[e], p1 = csr[e + 1], p2 = csr[e + 2], p3 = csr[e + 3];
        u16x8 u0 = hw8[(size_t)p0.x * 16 + f];
        u16x8 u1 = hw8[(size_t)p1.x * 16 + f];
        u16x8 u2 = hw8[(size_t)p2.x * 16 + f];
        u16x8 u3 = hw8[(size_t)p3.x * 16 + f];
        float c0 = __int_as_float(p0.y), c1 = __int_as_float(p1.y);
        float c2 = __int_as_float(p2.y), c3 = __int_as_float(p3.y);
#pragma unroll
        for (int j = 0; j < 8; j++) acc[j] = fmaf(c0, bf2f(u0[j]), acc[j]);
#pragma unroll
        for (int j = 0; j < 8; j++) acc[j] = fmaf(c1, bf2f(u1[j]), acc[j]);
#pragma unroll
        for (int j = 0; j < 8; j++) acc[j] = fmaf(c2, bf2f(u2[j]), acc[j]);
#pragma unroll
        for (int j = 0; j < 8; j++) acc[j] = fmaf(c3, bf2f(u3[j]), acc[j]);
    }
    for (; e + 1 < e1; e += 2) {
        int2 p0 = csr[e], p1 = csr[e + 1];
        u16x8 u0 = hw8[(size_t)p0.x * 16 + f];
        u16x8 u1 = hw8[(size_t)p1.x * 16 + f];
        float c0 = __int_as_float(p0.y), c1 = __int_as_float(p1.y);
#pragma unroll
        for (int j = 0; j < 8; j++) acc[j] = fmaf(c0, bf2f(u0[j]), acc[j]);
#pragma unroll
        for (int j = 0; j < 8; j++) acc[j] = fmaf(c1, bf2f(u1[j]), acc[j]);
    }
    if (e < e1) {
        int2 p0 = csr[e];
        u16x8 u0 = hw8[(size_t)p0.x * 16 + f];
        float c0 = __int_as_float(p0.y);
#pragma unroll
        for (int j = 0; j < 8; j++) acc[j] = fmaf(c0, bf2f(u0[j]), acc[j]);
    }

    const float4* b4 = (const float4*)bias;
    float4 ba = b4[f * 2], bb = b4[f * 2 + 1];
    float bv[8] = {ba.x, ba.y, ba.z, ba.w, bb.x, bb.y, bb.z, bb.w};
    u16x8 o;
#pragma unroll
    for (int j = 0; j < 8; j++) {
        float r = acc[j] + bv[j];
        if (do_relu) r = fmaxf(r, 0.f);
        o[j] = f2bf(r);
    }
    *((u16x8*)out + (size_t)node * 16 + f) = o;
}

// ---------------------------------------------------------------------------
// final aggregation, 40 bf16 features -> fp32 out.
// Block 320: 16 nodes, 20 lanes/node, 2 features (u16x2 = 4B) per lane.
// ---------------------------------------------------------------------------
__global__ __launch_bounds__(320) void agg40_bf16(const u16* __restrict__ g3,
                                                  const float* __restrict__ dinv,
                                                  const int* __restrict__ row_start,
                                                  const int2* __restrict__ csr,
                                                  const float* __restrict__ bias,
                                                  float* __restrict__ out, int n) {
    int t = threadIdx.x;
    int node = blockIdx.x * 16 + t / 20;
    int fq = t % 20;                    // features 2fq, 2fq+1
    if (node >= n) return;
    float di = dinv[node];
    float s2 = di * di;
    u16x2 v = *(const u16x2*)(g3 + (size_t)node * 40 + fq * 2);
    float a0 = bf2f(v[0]) * s2;
    float a1 = bf2f(v[1]) * s2;

    int e0 = row_start[node], e1 = row_start[node + 1];
    int e = e0;
    for (; e + 3 < e1; e += 4) {
        int2 p0 = csr[e], p1 = csr[e + 1], p2 = csr[e + 2], p3 = csr[e + 3];
        u16x2 u0 = *(const u16x2*)(g3 + (size_t)p0.x * 40 + fq * 2);
        u16x2 u1 = *(const u16x2*)(g3 + (size_t)p1.x * 40 + fq * 2);
        u16x2 u2 = *(const u16x2*)(g3 + (size_t)p2.x * 40 + fq * 2);
        u16x2 u3 = *(const u16x2*)(g3 + (size_t)p3.x * 40 + fq * 2);
        float c0 = __int_as_float(p0.y), c1 = __int_as_float(p1.y);
        float c2 = __int_as_float(p2.y), c3 = __int_as_float(p3.y);
        a0 = fmaf(c0, bf2f(u0[0]), a0); a1 = fmaf(c0, bf2f(u0[1]), a1);
        a0 = fmaf(c1, bf2f(u1[0]), a0); a1 = fmaf(c1, bf2f(u1[1]), a1);
        a0 = fmaf(c2, bf2f(u2[0]), a0); a1 = fmaf(c2, bf2f(u2[1]), a1);
        a0 = fmaf(c3, bf2f(u3[0]), a0); a1 = fmaf(c3, bf2f(u3[1]), a1);
    }
    for (; e + 1 < e1; e += 2) {
        int2 p0 = csr[e], p1 = csr[e + 1];
        u16x2 u0 = *(const u16x2*)(g3 + (size_t)p0.x * 40 + fq * 2);
        u16x2 u1 = *(const u16x2*)(g3 + (size_t)p1.x * 40 + fq * 2);
        float c0 = __int_as_float(p0.y), c1 = __int_as_float(p1.y);
        a0 = fmaf(c0, bf2f(u0[0]), a0); a1 = fmaf(c0, bf2f(u0[1]), a1);
        a0 = fmaf(c1, bf2f(u1[0]), a0); a1 = fmaf(c1, bf2f(u1[1]), a1);
    }
    if (e < e1) {
        int2 p0 = csr[e];
        u16x2 u0 = *(const u16x2*)(g3 + (size_t)p0.x * 40 + fq * 2);
        float c0 = __int_as_float(p0.y);
        a0 = fmaf(c0, bf2f(u0[0]), a0); a1 = fmaf(c0, bf2f(u0[1]), a1);
    }

    float2 b2v = *(const float2*)(bias + fq * 2);
    float2 o = make_float2(a0 + b2v.x, a1 + b2v.y);
    *(float2*)(out + (size_t)node * 40 + fq * 2) = o;
}

extern "C" void kernel_launch(void* const* d_in, const int* in_sizes, int n_in,
                              void* d_out, int out_size, void* d_ws, size_t ws_size,
                              hipStream_t stream) {
    const float* x  = (const float*)d_in[0];
    const int*   ei = (const int*)d_in[1];
    const float* W1 = (const float*)d_in[2];
    const float* b1 = (const float*)d_in[3];
    const float* W2 = (const float*)d_in[4];
    const float* b2 = (const float*)d_in[5];
    const float* W3 = (const float*)d_in[6];
    const float* b3 = (const float*)d_in[7];
    float* out = (float*)d_out;

    const int n = in_sizes[0] / 128;   // 170000
    const int E = in_sizes[1] / 2;     // 1200000

    // workspace carve (256B aligned)
    char* p = (char*)d_ws;
    auto alloc = [&](size_t bytes) { void* r = (void*)p; p += (bytes + 255) & ~(size_t)255; return r; };
    int*   cnt       = (int*)alloc((size_t)n * 4);
    int*   row_start = (int*)alloc((size_t)(n + 1) * 4);
    int*   cursor    = (int*)alloc((size_t)n * 4);
    int*   bsum      = (int*)alloc(1024 * 4);
    int*   boff      = (int*)alloc(1024 * 4);
    float* dinv      = (float*)alloc((size_t)n * 4);
    int2*  csr       = (int2*)alloc((size_t)E * 8);
    u16*   bufG      = (u16*)alloc((size_t)n * 128 * 2);   // gemm outputs (bf16)
    u16*   bufH      = (u16*)alloc((size_t)n * 128 * 2);   // agg outputs (bf16)
    u16*   g3b       = (u16*)alloc((size_t)n * 40 * 2);    // layer-3 gemm out (bf16)
    u16*   wt1       = (u16*)alloc(16384 * 2);
    u16*   wt2       = (u16*)alloc(16384 * 2);
    u16*   wt3       = (u16*)alloc(8192 * 2);              // [64][128], cols 40+ zero

    // --- weight convert (one launch: W1, W2, W3pad) ---
    wconv_all<<<160, 256, 0, stream>>>(W1, W2, W3, wt1, wt2, wt3);

    // --- CSR build ---
    hipMemsetAsync(cnt, 0, (size_t)n * 4, stream);
    count_kernel<<<(E + 255) / 256, 256, 0, stream>>>(ei, E, cnt);
    int nb = (n + 1023) / 1024;
    scan1_kernel<<<nb, 256, 0, stream>>>(cnt, row_start, bsum, dinv, n);
    scan2_kernel<<<1, 256, 0, stream>>>(bsum, boff, row_start, nb, n);
    scan3_kernel<<<nb, 256, 0, stream>>>(row_start, cursor, boff, n);
    fill_kernel<<<(E + 255) / 256, 256, 0, stream>>>(ei, E, cursor, dinv, csr);

    const int gblk = (n + 127) / 128;

    // --- layer 1 (A fp32) ---
    gemm128_mfma<false><<<gblk, 256, 0, stream>>>(x, wt1, bufG, n);
    agg128_bf16<<<(n + 15) / 16, 256, 0, stream>>>(bufG, dinv, row_start, csr, b1, bufH, n, 1);
    // --- layer 2 (A bf16) ---
    gemm128_mfma<true><<<gblk, 256, 0, stream>>>(bufH, wt2, bufG, n);
    agg128_bf16<<<(n + 15) / 16, 256, 0, stream>>>(bufG, dinv, row_start, csr, b2, bufH, n, 1);
    // --- layer 3 (W first: A(hW3) == (Ah)W3, aggregate only 40 features) ---
    gemm40_mfma<<<gblk, 256, 0, stream>>>(bufH, wt3, g3b, n);
    agg40_bf16<<<(n + 15) / 16, 320, 0, stream>>>(g3b, dinv, row_start, csr, b3, out, n);
}